// Round 12
// baseline (180.012 us; speedup 1.0000x reference)
//
#include <hip/hip_runtime.h>

typedef short bf16x8 __attribute__((ext_vector_type(8)));
typedef float f32x4 __attribute__((ext_vector_type(4)));
typedef float f32x2 __attribute__((ext_vector_type(2)));
typedef unsigned short u16x4 __attribute__((ext_vector_type(4)));
typedef unsigned short u16x2 __attribute__((ext_vector_type(2)));

#define MFMA16(A, B, C) __builtin_amdgcn_mfma_f32_16x16x32_bf16((A), (B), (C), 0, 0, 0)

static constexpr int NB = 4;       // batch
static constexpr int CC = 256;     // channels (INC1 == INC2)
static constexpr int NN = 4096;    // H*W
static constexpr int DD = 64;      // head dim

__device__ __forceinline__ unsigned short f2bf(float f) {
  unsigned int u = __builtin_bit_cast(unsigned int, f);
  u += 0x7fffu + ((u >> 16) & 1u);
  return (unsigned short)(u >> 16);
}

__device__ __forceinline__ unsigned int pk2(float lo, float hi) {
  return (unsigned int)f2bf(lo) | ((unsigned int)f2bf(hi) << 16);
}

// T12 recipe: packed f32->bf16x2 convert (RNE), 1 instruction.
__device__ __forceinline__ unsigned int cvtpk(float lo, float hi) {
  unsigned int r;
  asm("v_cvt_pk_bf16_f32 %0, %1, %2" : "=v"(r) : "v"(lo), "v"(hi));
  return r;
}

// LDS 16B-slot swizzle (R5-verified)
__device__ __forceinline__ int swz16(int row) {
  return ((row & 3) | ((((row >> 2) ^ (row >> 3)) & 1) << 2)) << 4;
}

// ---------------------------------------------------------------------------
// Kernel 1: fold BN into projection weights. Grid 16 (R11-verified).
// ---------------------------------------------------------------------------
__global__ __launch_bounds__(256) void prep_kernel(
    const float* __restrict__ kq1_w, const float* __restrict__ kq1_b,
    const float* __restrict__ kq2_w, const float* __restrict__ kq2_b,
    const float* __restrict__ v_w,   const float* __restrict__ v_b,
    const float* __restrict__ out_w, const float* __restrict__ out_b,
    const float* __restrict__ bn1_g, const float* __restrict__ bn1_b,
    const float* __restrict__ bn1_m, const float* __restrict__ bn1_v,
    const float* __restrict__ bn2_g, const float* __restrict__ bn2_b,
    const float* __restrict__ bn2_m, const float* __restrict__ bn2_v,
    const float* __restrict__ bnl_g, const float* __restrict__ bnl_b,
    const float* __restrict__ bnl_m, const float* __restrict__ bnl_v,
    const float* __restrict__ w_scale,
    unsigned short* __restrict__ W1, unsigned short* __restrict__ W2,
    unsigned short* __restrict__ WV, unsigned short* __restrict__ WO,
    float* __restrict__ B1, float* __restrict__ B2,
    float* __restrict__ BV, float* __restrict__ BO)
{
  int blk = blockIdx.x;
  int tid = threadIdx.x;
  int w = tid >> 6, lane = tid & 63;
  if (blk < 12) {
    int mat = blk >> 2, rg = blk & 3;
    const float* Wsrc = mat == 0 ? kq1_w : (mat == 1 ? kq2_w : v_w);
    const float* bsrc = mat == 0 ? kq1_b : (mat == 1 ? kq2_b : v_b);
    unsigned short* Wdst = mat == 0 ? W1 : (mat == 1 ? W2 : WV);
    float* Bdst = mat == 0 ? B1 : (mat == 1 ? B2 : BV);
    __shared__ float s_lds[256], o_lds[256];
    if (mat == 0) {
      float s = bn1_g[tid] * rsqrtf(bn1_v[tid] + 1e-5f);
      s_lds[tid] = s;
      o_lds[tid] = bn1_b[tid] - bn1_m[tid] * s;
    } else if (mat == 1) {
      float s = bn2_g[tid] * rsqrtf(bn2_v[tid] + 1e-5f);
      s_lds[tid] = s;
      o_lds[tid] = bn2_b[tid] - bn2_m[tid] * s;
    } else {
      s_lds[tid] = 1.f;
      o_lds[tid] = 0.f;
    }
    __syncthreads();
    int c = lane * 4;
    for (int row = rg * 32 + w; row < rg * 32 + 32; row += 4) {
      f32x4 wv = *(const f32x4*)(Wsrc + row * CC + c);
      u16x4 o;
      float bacc = 0.f;
#pragma unroll
      for (int j = 0; j < 4; ++j) {
        o[j] = f2bf(wv[j] * s_lds[c + j]);
        bacc += wv[j] * o_lds[c + j];
      }
      *(u16x4*)(Wdst + row * CC + c) = o;
#pragma unroll
      for (int off = 1; off < 64; off <<= 1) bacc += __shfl_xor(bacc, off);
      if (lane == 0) Bdst[row] = bsrc[row] + bacc;
    }
  } else {
    int rg = blk - 12;
    float ws = w_scale[0];
    if (rg == 0) {
      float s = bnl_g[tid] * rsqrtf(bnl_v[tid] + 1e-5f);
      BO[tid] = ws * (out_b[tid] * s + bnl_b[tid] - bnl_m[tid] * s);
    }
    int d = lane * 2;
    for (int row = rg * 64 + w; row < rg * 64 + 64; row += 4) {
      float s = ws * bnl_g[row] * rsqrtf(bnl_v[row] + 1e-5f);
      f32x2 wv = *(const f32x2*)(out_w + row * 128 + d);
      u16x2 o;
      o[0] = f2bf(s * wv[0]);
      o[1] = f2bf(s * wv[1]);
      *(u16x2*)(WO + row * 128 + d) = o;
    }
  }
}

// ---------------------------------------------------------------------------
// Kernel 2: NCHW f32 -> (b, n, c) bf16 transpose-cast via LDS 64x64 tiles.
// ---------------------------------------------------------------------------
__global__ __launch_bounds__(256) void conv_kernel(
    const float* __restrict__ x, const float* __restrict__ x1, const float* __restrict__ x2,
    unsigned short* __restrict__ t0, unsigned short* __restrict__ t1, unsigned short* __restrict__ t2)
{
  int tensor = blockIdx.z >> 2, b = blockIdx.z & 3;
  const float* src = tensor == 0 ? x : (tensor == 1 ? x1 : x2);
  unsigned short* dst = tensor == 0 ? t0 : (tensor == 1 ? t1 : t2);
  int cb = blockIdx.y * 64, nb = blockIdx.x * 64;
  __shared__ float tile[64][65];
  int t = threadIdx.x;
  int cl = t >> 2, n0 = (t & 3) * 16;
  const float* s = src + ((size_t)b * CC + cb + cl) * NN + nb + n0;
  f32x4 v0 = *(const f32x4*)(s);
  f32x4 v1 = *(const f32x4*)(s + 4);
  f32x4 v2 = *(const f32x4*)(s + 8);
  f32x4 v3 = *(const f32x4*)(s + 12);
#pragma unroll
  for (int j = 0; j < 4; ++j) {
    tile[cl][n0 + j] = v0[j];
    tile[cl][n0 + 4 + j] = v1[j];
    tile[cl][n0 + 8 + j] = v2[j];
    tile[cl][n0 + 12 + j] = v3[j];
  }
  __syncthreads();
  int nl = t >> 2, c0 = (t & 3) * 16;
  unsigned short* d = dst + ((size_t)b * NN + nb + nl) * CC + cb + c0;
  alignas(16) unsigned short tmp[16];
#pragma unroll
  for (int j = 0; j < 16; ++j) tmp[j] = f2bf(tile[c0 + j][nl]);
  *(bf16x8*)(d) = *(const bf16x8*)(tmp);
  *(bf16x8*)(d + 8) = *(const bf16x8*)(tmp + 8);
}

// ---------------------------------------------------------------------------
// Kernel 3: projections. Q pre-scaled by 0.125*log2(e) (exp2-domain softmax).
// ---------------------------------------------------------------------------
__global__ __launch_bounds__(256) void proj_kernel(
    const unsigned short* __restrict__ Xt0, const unsigned short* __restrict__ Xt1,
    const unsigned short* __restrict__ Xt2,
    const unsigned short* __restrict__ W1, const unsigned short* __restrict__ W2,
    const unsigned short* __restrict__ WV,
    const float* __restrict__ B1, const float* __restrict__ B2, const float* __restrict__ BV,
    unsigned short* __restrict__ Qb, unsigned short* __restrict__ Kb,
    unsigned short* __restrict__ Vt)
{
  int nt = blockIdx.x;
  int mat = blockIdx.y;
  int b = blockIdx.z;
  const unsigned short* X =
      (mat == 0 ? Xt1 : (mat == 1 ? Xt2 : Xt0)) + (size_t)b * NN * CC;
  const unsigned short* W = mat == 0 ? W1 : (mat == 1 ? W2 : WV);
  const float* Bi = mat == 0 ? B1 : (mat == 1 ? B2 : BV);
  int w = threadIdx.x >> 6, lane = threadIdx.x & 63;
  int lhi = lane >> 4, llo = lane & 15;
  int ob = w * 32;

  f32x4 acc[2][4] = {};
#pragma unroll
  for (int kc = 0; kc < 8; ++kc) {
    bf16x8 af[2], bfr[4];
#pragma unroll
    for (int ot = 0; ot < 2; ++ot)
      af[ot] = *(const bf16x8*)(W + (size_t)(ob + ot * 16 + llo) * CC + kc * 32 + lhi * 8);
#pragma unroll
    for (int nn = 0; nn < 4; ++nn)
      bfr[nn] = *(const bf16x8*)(X + ((size_t)nt * 64 + nn * 16 + llo) * CC + kc * 32 + lhi * 8);
#pragma unroll
    for (int ot = 0; ot < 2; ++ot)
#pragma unroll
      for (int nn = 0; nn < 4; ++nn)
        acc[ot][nn] = MFMA16(af[ot], bfr[nn], acc[ot][nn]);
  }

#pragma unroll
  for (int ot = 0; ot < 2; ++ot)
#pragma unroll
    for (int nn = 0; nn < 4; ++nn)
#pragma unroll
      for (int r = 0; r < 4; ++r) {
        int o = ob + ot * 16 + lhi * 4 + r;
        int n = nt * 64 + nn * 16 + llo;
        float val = acc[ot][nn][r] + Bi[o];
        if (mat < 2) {
          int blk = o >> 5;              // 0:K a0  1:Q a0  2:K a1  3:Q a1
          int aa = blk >> 1;
          int d = (o & 31) + mat * 32;
          if (blk & 1) val *= 0.18033688011f;   // 0.125 * log2(e)
          unsigned short* dstp = (blk & 1) ? Qb : Kb;
          dstp[((size_t)(b * 2 + aa) * NN + n) * DD + d] = f2bf(val);
        } else {
          int aa = o >> 6, d = o & 63;
          Vt[((size_t)(b * 2 + aa) * DD + d) * NN + n] = f2bf(val);
        }
      }
}

// ---------------------------------------------------------------------------
// Kernel 4: flash attention, swapped-QK^T, R8-verified per-wave structure
// (32 q-rows/wave, exp2 softmax, cvt_pk, defer-rescale), now 8 waves/block:
// 2 wq (32q each) x 4 wk (1024-k quarters). Single-buffered per-quarter K/V
// (4 x 16KB = 64KB) -> 2 blocks/CU = 16 waves/CU = 4 waves/SIMD (2x R11's
// latency hiding). 16 iters/wave; 4-way merge epilogue.
// ---------------------------------------------------------------------------
__global__ __launch_bounds__(512, 4) void attn_kernel(
    const unsigned short* __restrict__ Qb, const unsigned short* __restrict__ Kb,
    const unsigned short* __restrict__ Vt, unsigned short* __restrict__ Ob)
{
  int qt = blockIdx.x;                  // 64-q tile
  int a = blockIdx.y;
  int b = blockIdx.z;
  int ba = b * 2 + a;
  int tid = threadIdx.x;
  int w = tid >> 6;                     // 0..7
  int lane = tid & 63;
  int lhi = lane >> 4, llo = lane & 15;
  int wq = w & 1, wk = w >> 1;          // wk in 0..3: 1024-k quarter

  __shared__ char lds[65536];           // [wk][ K 8KB | V 8KB ] single-buf

  char* Ks = lds + wk * 16384;
  char* Vs = Ks + 8192;

  // Q as B-operand: qf[qh][h], lane holds Q[q = qh*16+llo][d = h*32+lhi*8..+8]
  const unsigned short* Qg = Qb + ((size_t)ba * NN + qt * 64 + wq * 32) * DD;
  bf16x8 qf[2][2];
#pragma unroll
  for (int qh = 0; qh < 2; ++qh)
#pragma unroll
    for (int h = 0; h < 2; ++h)
      qf[qh][h] = *(const bf16x8*)(Qg + (size_t)(qh * 16 + llo) * DD + h * 32 + lhi * 8);

  const unsigned short* Kg = Kb + ((size_t)ba * NN + wk * 1024) * DD;
  const unsigned short* Vg = Vt + (size_t)ba * DD * NN + wk * 1024;

  f32x4 oacc[2][4] = {};
  float m[2] = {-1e30f, -1e30f}, lsum[2] = {0.f, 0.f};

  // staging: the 128 threads of quarter wk (waves 2wk, 2wk+1) stage its tile
  int t7 = tid & 127;
  int sr8 = t7 >> 3, scol = t7 & 7;

  f32x4 kreg[4], vreg[4];
#define STAGE_LOAD(IT)                                                        \
  {                                                                           \
    int kb_ = (IT) * 64;                                                      \
    _Pragma("unroll") for (int i = 0; i < 4; ++i) {                           \
      int row = i * 16 + sr8;                                                 \
      kreg[i] = *(const f32x4*)(Kg + (size_t)(kb_ + row) * DD + scol * 8);    \
      vreg[i] = *(const f32x4*)(Vg + (size_t)row * NN + kb_ + scol * 8);      \
    }                                                                         \
  }
#define STAGE_WRITE()                                                        \
  {                                                                           \
    _Pragma("unroll") for (int i = 0; i < 4; ++i) {                           \
      int row = i * 16 + sr8;                                                 \
      int swz = (scol * 16) ^ swz16(row);                                     \
      *(f32x4*)(Ks + row * 128 + swz) = kreg[i];                              \
      *(f32x4*)(Vs + row * 128 + swz) = vreg[i];                              \
    }                                                                         \
  }

  STAGE_LOAD(0);
  STAGE_WRITE();
  __syncthreads();

  for (int it = 0; it < 16; ++it) {
    if (it < 15) STAGE_LOAD(it + 1);

    // S^T = K_perm @ Q (K fragment shared by both qh)
    f32x4 s[2][4] = {};
    __builtin_amdgcn_s_setprio(1);
#pragma unroll
    for (int t = 0; t < 4; ++t) {
      int krow = (t & 1) * 32 + ((llo >> 2) << 3) + ((t >> 1) << 2) + (llo & 3);
      int ksz = swz16(krow);
      const char* kp = Ks + krow * 128;
      bf16x8 k0 = *(const bf16x8*)(kp + ((lhi * 16) ^ ksz));
      bf16x8 k1 = *(const bf16x8*)(kp + ((64 + lhi * 16) ^ ksz));
      s[0][t] = MFMA16(k0, qf[0][0], s[0][t]);
      s[0][t] = MFMA16(k1, qf[0][1], s[0][t]);
      s[1][t] = MFMA16(k0, qf[1][0], s[1][t]);
      s[1][t] = MFMA16(k1, qf[1][1], s[1][t]);
    }
    __builtin_amdgcn_s_setprio(0);

    // online softmax per qh (exp2 domain; lane owns one q per qh)
    union { unsigned int u[4]; bf16x8 v; } F0[2], F1[2];
#pragma unroll
    for (int qh = 0; qh < 2; ++qh) {
      float t0 = fmaxf(fmaxf(s[qh][0][0], s[qh][0][1]), fmaxf(s[qh][0][2], s[qh][0][3]));
      float t1 = fmaxf(fmaxf(s[qh][1][0], s[qh][1][1]), fmaxf(s[qh][1][2], s[qh][1][3]));
      float t2 = fmaxf(fmaxf(s[qh][2][0], s[qh][2][1]), fmaxf(s[qh][2][2], s[qh][2][3]));
      float t3 = fmaxf(fmaxf(s[qh][3][0], s[qh][3][1]), fmaxf(s[qh][3][2], s[qh][3][3]));
      float pm = fmaxf(fmaxf(t0, t1), fmaxf(t2, t3));
      pm = fmaxf(pm, __shfl_xor(pm, 16));
      pm = fmaxf(pm, __shfl_xor(pm, 32));
      if (__any(pm > m[qh])) {   // exact skip: pm<=m everywhere => al==1
        float mn = fmaxf(m[qh], pm);
        float al = __builtin_amdgcn_exp2f(m[qh] - mn);
        m[qh] = mn;
        lsum[qh] *= al;
#pragma unroll
        for (int dt = 0; dt < 4; ++dt)
#pragma unroll
          for (int r = 0; r < 4; ++r) oacc[qh][dt][r] *= al;
      }
#pragma unroll
      for (int t = 0; t < 4; ++t)
#pragma unroll
        for (int r = 0; r < 4; ++r)
          s[qh][t][r] = __builtin_amdgcn_exp2f(s[qh][t][r] - m[qh]);
      float p0 = (s[qh][0][0] + s[qh][0][1]) + (s[qh][0][2] + s[qh][0][3]);
      float p1 = (s[qh][1][0] + s[qh][1][1]) + (s[qh][1][2] + s[qh][1][3]);
      float p2 = (s[qh][2][0] + s[qh][2][1]) + (s[qh][2][2] + s[qh][2][3]);
      float p3 = (s[qh][3][0] + s[qh][3][1]) + (s[qh][3][2] + s[qh][3][3]);
      lsum[qh] += (p0 + p1) + (p2 + p3);

      F0[qh].u[0] = cvtpk(s[qh][0][0], s[qh][0][1]); F0[qh].u[1] = cvtpk(s[qh][0][2], s[qh][0][3]);
      F0[qh].u[2] = cvtpk(s[qh][2][0], s[qh][2][1]); F0[qh].u[3] = cvtpk(s[qh][2][2], s[qh][2][3]);
      F1[qh].u[0] = cvtpk(s[qh][1][0], s[qh][1][1]); F1[qh].u[1] = cvtpk(s[qh][1][2], s[qh][1][3]);
      F1[qh].u[2] = cvtpk(s[qh][3][0], s[qh][3][1]); F1[qh].u[3] = cvtpk(s[qh][3][2], s[qh][3][3]);
    }

    // O^T += V^T @ P^T (V fragment shared by both qh)
    __builtin_amdgcn_s_setprio(1);
#pragma unroll
    for (int dt = 0; dt < 4; ++dt) {
      int vrow = dt * 16 + llo;
      int vsz = swz16(vrow);
      const char* vp = Vs + vrow * 128;
      bf16x8 v0 = *(const bf16x8*)(vp + ((lhi * 16) ^ vsz));
      bf16x8 v1 = *(const bf16x8*)(vp + ((64 + lhi * 16) ^ vsz));
      oacc[0][dt] = MFMA16(v0, F0[0].v, oacc[0][dt]);
      oacc[0][dt] = MFMA16(v1, F1[0].v, oacc[0][dt]);
      oacc[1][dt] = MFMA16(v0, F0[1].v, oacc[1][dt]);
      oacc[1][dt] = MFMA16(v1, F1[1].v, oacc[1][dt]);
    }
    __builtin_amdgcn_s_setprio(0);

    __syncthreads();
    if (it < 15) STAGE_WRITE();
    __syncthreads();
  }

  // full row sums across the 4 lanes sharing each q
#pragma unroll
  for (int qh = 0; qh < 2; ++qh) {
    lsum[qh] += __shfl_xor(lsum[qh], 16);
    lsum[qh] += __shfl_xor(lsum[qh], 32);
  }

  // 4-way merge: wk 1..3 publish partials (stride-65 rows); wk0 combines.
  float* mO = (float*)lds;                 // [(wk-1)*64 + ql][65]
  float* mM = (float*)(lds + 50176);       // [3][64]
  float* mL = mM + 192;
  if (wk != 0) {
#pragma unroll
    for (int qh = 0; qh < 2; ++qh) {
      int ql = wq * 32 + qh * 16 + llo;
      int rowi = (wk - 1) * 64 + ql;
#pragma unroll
      for (int dt = 0; dt < 4; ++dt)
#pragma unroll
        for (int r = 0; r < 4; ++r)
          mO[rowi * 65 + dt * 16 + lhi * 4 + r] = oacc[qh][dt][r];
      if (lhi == 0) { mM[rowi] = m[qh]; mL[rowi] = lsum[qh]; }
    }
  }
  __syncthreads();
  if (wk == 0) {
#pragma unroll
    for (int qh = 0; qh < 2; ++qh) {
      int ql = wq * 32 + qh * 16 + llo;
      float mf = m[qh];
      float mp[3], lp[3];
#pragma unroll
      for (int p = 0; p < 3; ++p) {
        mp[p] = mM[p * 64 + ql];
        lp[p] = mL[p * 64 + ql];
        mf = fmaxf(mf, mp[p]);
      }
      float e0 = __builtin_amdgcn_exp2f(m[qh] - mf);
      float L = lsum[qh] * e0;
      float ep[3];
#pragma unroll
      for (int p = 0; p < 3; ++p) {
        ep[p] = __builtin_amdgcn_exp2f(mp[p] - mf);
        L += lp[p] * ep[p];
      }
      float inv = 1.f / L;
      int qglob = qt * 64 + ql;
      unsigned int* dst = (unsigned int*)(Ob + ((size_t)b * NN + qglob) * 128 + a * 64);
#pragma unroll
      for (int dt = 0; dt < 4; ++dt) {
        int d0 = dt * 16 + lhi * 4;
        float v[4];
#pragma unroll
        for (int r = 0; r < 4; ++r) {
          float acc = oacc[qh][dt][r] * e0;
#pragma unroll
          for (int p = 0; p < 3; ++p) acc += mO[(p * 64 + ql) * 65 + d0 + r] * ep[p];
          v[r] = acc * inv;
        }
        dst[dt * 8 + lhi * 2] = pk2(v[0], v[1]);
        dst[dt * 8 + lhi * 2 + 1] = pk2(v[2], v[3]);
      }
    }
  }
}

// ---------------------------------------------------------------------------
// Kernel 5: OUT[b,c,n] = sum_d WO[c,d]*O[b,n,d] + BO[c] + x[b,c,n]
// ---------------------------------------------------------------------------
__global__ __launch_bounds__(256) void out_kernel(
    const unsigned short* __restrict__ Ob, const unsigned short* __restrict__ WO,
    const float* __restrict__ BO, const float* __restrict__ x,
    float* __restrict__ out)
{
  int nt = blockIdx.x;
  int ct = blockIdx.y;
  int b = blockIdx.z;
  int w = threadIdx.x >> 6, lane = threadIdx.x & 63;
  int lhi = lane >> 4, llo = lane & 15;
  int cb = ct * 64 + w * 16;

  f32x4 acc[4] = {};
#pragma unroll
  for (int kc = 0; kc < 4; ++kc) {
    bf16x8 af = *(const bf16x8*)(WO + (size_t)(cb + llo) * 128 + kc * 32 + lhi * 8);
#pragma unroll
    for (int nn = 0; nn < 4; ++nn) {
      bf16x8 bfr = *(const bf16x8*)(Ob + ((size_t)b * NN + nt * 64 + nn * 16 + llo) * 128 + kc * 32 + lhi * 8);
      acc[nn] = MFMA16(af, bfr, acc[nn]);
    }
  }
#pragma unroll
  for (int nn = 0; nn < 4; ++nn)
#pragma unroll
    for (int r = 0; r < 4; ++r) {
      int c = cb + lhi * 4 + r;
      int n = nt * 64 + nn * 16 + llo;
      size_t idx = ((size_t)b * CC + c) * NN + n;
      out[idx] = acc[nn][r] + BO[c] + x[idx];
    }
}

// ---------------------------------------------------------------------------
extern "C" void kernel_launch(void* const* d_in, const int* in_sizes, int n_in,
                              void* d_out, int out_size, void* d_ws, size_t ws_size,
                              hipStream_t stream) {
  const float* x = (const float*)d_in[0];
  const float* x1 = (const float*)d_in[1];
  const float* x2 = (const float*)d_in[2];
  const float* bn1_g = (const float*)d_in[3];
  const float* bn1_b = (const float*)d_in[4];
  const float* bn1_m = (const float*)d_in[5];
  const float* bn1_v = (const float*)d_in[6];
  const float* bn2_g = (const float*)d_in[7];
  const float* bn2_b = (const float*)d_in[8];
  const float* bn2_m = (const float*)d_in[9];
  const float* bn2_v = (const float*)d_in[10];
  const float* kq1_w = (const float*)d_in[11];
  const float* kq1_b = (const float*)d_in[12];
  const float* kq2_w = (const float*)d_in[13];
  const float* kq2_b = (const float*)d_in[14];
  const float* v_w = (const float*)d_in[15];
  const float* v_b = (const float*)d_in[16];
  const float* out_w = (const float*)d_in[17];
  const float* out_b = (const float*)d_in[18];
  const float* bnl_g = (const float*)d_in[19];
  const float* bnl_b = (const float*)d_in[20];
  const float* bnl_m = (const float*)d_in[21];
  const float* bnl_v = (const float*)d_in[22];
  const float* w_scale = (const float*)d_in[23];

  char* ws = (char*)d_ws;
  const size_t XT_SZ = (size_t)NB * NN * CC * 2;        // 8 MB each
  const size_t QKV_SZ = (size_t)NB * 2 * NN * DD * 2;   // 4 MB each
  size_t off = 0;
  unsigned short* XT0 = (unsigned short*)(ws + off); off += XT_SZ;
  unsigned short* XT1 = (unsigned short*)(ws + off); off += XT_SZ;
  unsigned short* XT2 = (unsigned short*)(ws + off); off += XT_SZ;
  unsigned short* Qb = (unsigned short*)(ws + off); off += QKV_SZ;
  unsigned short* Kb = (unsigned short*)(ws + off); off += QKV_SZ;
  unsigned short* Vt = (unsigned short*)(ws + off); off += QKV_SZ;
  unsigned short* Ob = (unsigned short*)(ws + off); off += (size_t)NB * NN * 128 * 2;
  unsigned short* W1 = (unsigned short*)(ws + off); off += 128 * CC * 2;
  unsigned short* W2 = (unsigned short*)(ws + off); off += 128 * CC * 2;
  unsigned short* WV = (unsigned short*)(ws + off); off += 128 * CC * 2;
  unsigned short* WO = (unsigned short*)(ws + off); off += CC * 128 * 2;
  float* B1 = (float*)(ws + off); off += 512;
  float* B2 = (float*)(ws + off); off += 512;
  float* BV = (float*)(ws + off); off += 512;
  float* BO = (float*)(ws + off); off += 1024;
  if (ws_size < off) return;  // loud failure: output stays poisoned

  prep_kernel<<<16, 256, 0, stream>>>(
      kq1_w, kq1_b, kq2_w, kq2_b, v_w, v_b, out_w, out_b,
      bn1_g, bn1_b, bn1_m, bn1_v, bn2_g, bn2_b, bn2_m, bn2_v,
      bnl_g, bnl_b, bnl_m, bnl_v, w_scale,
      W1, W2, WV, WO, B1, B2, BV, BO);

  conv_kernel<<<dim3(64, 4, 12), 256, 0, stream>>>(x, x1, x2, XT0, XT1, XT2);

  proj_kernel<<<dim3(64, 3, 4), 256, 0, stream>>>(
      XT0, XT1, XT2, W1, W2, WV, B1, B2, BV, Qb, Kb, Vt);

  attn_kernel<<<dim3(64, 2, 4), 512, 0, stream>>>(Qb, Kb, Vt, Ob);

  out_kernel<<<dim3(64, 4, 4), 256, 0, stream>>>(Ob, WO, BO, x, (float*)d_out);
}

// Round 13
// 133.474 us; speedup vs baseline: 1.3487x; 1.3487x over previous
//
#include <hip/hip_runtime.h>

typedef short bf16x8 __attribute__((ext_vector_type(8)));
typedef float f32x4 __attribute__((ext_vector_type(4)));
typedef float f32x2 __attribute__((ext_vector_type(2)));
typedef unsigned short u16x4 __attribute__((ext_vector_type(4)));
typedef unsigned short u16x2 __attribute__((ext_vector_type(2)));

#define MFMA16(A, B, C) __builtin_amdgcn_mfma_f32_16x16x32_bf16((A), (B), (C), 0, 0, 0)

static constexpr int NB = 4;       // batch
static constexpr int CC = 256;     // channels (INC1 == INC2)
static constexpr int NN = 4096;    // H*W
static constexpr int DD = 64;      // head dim

__device__ __forceinline__ unsigned short f2bf(float f) {
  unsigned int u = __builtin_bit_cast(unsigned int, f);
  u += 0x7fffu + ((u >> 16) & 1u);
  return (unsigned short)(u >> 16);
}

__device__ __forceinline__ unsigned int pk2(float lo, float hi) {
  return (unsigned int)f2bf(lo) | ((unsigned int)f2bf(hi) << 16);
}

// T12 recipe: packed f32->bf16x2 convert (RNE), 1 instruction.
__device__ __forceinline__ unsigned int cvtpk(float lo, float hi) {
  unsigned int r;
  asm("v_cvt_pk_bf16_f32 %0, %1, %2" : "=v"(r) : "v"(lo), "v"(hi));
  return r;
}

// LDS 16B-slot swizzle (R5-verified)
__device__ __forceinline__ int swz16(int row) {
  return ((row & 3) | ((((row >> 2) ^ (row >> 3)) & 1) << 2)) << 4;
}

// ---------------------------------------------------------------------------
// Kernel 1: fold BN into projection weights. Grid 16 (R11-verified).
// ---------------------------------------------------------------------------
__global__ __launch_bounds__(256) void prep_kernel(
    const float* __restrict__ kq1_w, const float* __restrict__ kq1_b,
    const float* __restrict__ kq2_w, const float* __restrict__ kq2_b,
    const float* __restrict__ v_w,   const float* __restrict__ v_b,
    const float* __restrict__ out_w, const float* __restrict__ out_b,
    const float* __restrict__ bn1_g, const float* __restrict__ bn1_b,
    const float* __restrict__ bn1_m, const float* __restrict__ bn1_v,
    const float* __restrict__ bn2_g, const float* __restrict__ bn2_b,
    const float* __restrict__ bn2_m, const float* __restrict__ bn2_v,
    const float* __restrict__ bnl_g, const float* __restrict__ bnl_b,
    const float* __restrict__ bnl_m, const float* __restrict__ bnl_v,
    const float* __restrict__ w_scale,
    unsigned short* __restrict__ W1, unsigned short* __restrict__ W2,
    unsigned short* __restrict__ WV, unsigned short* __restrict__ WO,
    float* __restrict__ B1, float* __restrict__ B2,
    float* __restrict__ BV, float* __restrict__ BO)
{
  int blk = blockIdx.x;
  int tid = threadIdx.x;
  int w = tid >> 6, lane = tid & 63;
  if (blk < 12) {
    int mat = blk >> 2, rg = blk & 3;
    const float* Wsrc = mat == 0 ? kq1_w : (mat == 1 ? kq2_w : v_w);
    const float* bsrc = mat == 0 ? kq1_b : (mat == 1 ? kq2_b : v_b);
    unsigned short* Wdst = mat == 0 ? W1 : (mat == 1 ? W2 : WV);
    float* Bdst = mat == 0 ? B1 : (mat == 1 ? B2 : BV);
    __shared__ float s_lds[256], o_lds[256];
    if (mat == 0) {
      float s = bn1_g[tid] * rsqrtf(bn1_v[tid] + 1e-5f);
      s_lds[tid] = s;
      o_lds[tid] = bn1_b[tid] - bn1_m[tid] * s;
    } else if (mat == 1) {
      float s = bn2_g[tid] * rsqrtf(bn2_v[tid] + 1e-5f);
      s_lds[tid] = s;
      o_lds[tid] = bn2_b[tid] - bn2_m[tid] * s;
    } else {
      s_lds[tid] = 1.f;
      o_lds[tid] = 0.f;
    }
    __syncthreads();
    int c = lane * 4;
    for (int row = rg * 32 + w; row < rg * 32 + 32; row += 4) {
      f32x4 wv = *(const f32x4*)(Wsrc + row * CC + c);
      u16x4 o;
      float bacc = 0.f;
#pragma unroll
      for (int j = 0; j < 4; ++j) {
        o[j] = f2bf(wv[j] * s_lds[c + j]);
        bacc += wv[j] * o_lds[c + j];
      }
      *(u16x4*)(Wdst + row * CC + c) = o;
#pragma unroll
      for (int off = 1; off < 64; off <<= 1) bacc += __shfl_xor(bacc, off);
      if (lane == 0) Bdst[row] = bsrc[row] + bacc;
    }
  } else {
    int rg = blk - 12;
    float ws = w_scale[0];
    if (rg == 0) {
      float s = bnl_g[tid] * rsqrtf(bnl_v[tid] + 1e-5f);
      BO[tid] = ws * (out_b[tid] * s + bnl_b[tid] - bnl_m[tid] * s);
    }
    int d = lane * 2;
    for (int row = rg * 64 + w; row < rg * 64 + 64; row += 4) {
      float s = ws * bnl_g[row] * rsqrtf(bnl_v[row] + 1e-5f);
      f32x2 wv = *(const f32x2*)(out_w + row * 128 + d);
      u16x2 o;
      o[0] = f2bf(s * wv[0]);
      o[1] = f2bf(s * wv[1]);
      *(u16x2*)(WO + row * 128 + d) = o;
    }
  }
}

// ---------------------------------------------------------------------------
// Kernel 2: NCHW f32 -> (b, n, c) bf16 transpose-cast via LDS 64x64 tiles.
// ---------------------------------------------------------------------------
__global__ __launch_bounds__(256) void conv_kernel(
    const float* __restrict__ x, const float* __restrict__ x1, const float* __restrict__ x2,
    unsigned short* __restrict__ t0, unsigned short* __restrict__ t1, unsigned short* __restrict__ t2)
{
  int tensor = blockIdx.z >> 2, b = blockIdx.z & 3;
  const float* src = tensor == 0 ? x : (tensor == 1 ? x1 : x2);
  unsigned short* dst = tensor == 0 ? t0 : (tensor == 1 ? t1 : t2);
  int cb = blockIdx.y * 64, nb = blockIdx.x * 64;
  __shared__ float tile[64][65];
  int t = threadIdx.x;
  int cl = t >> 2, n0 = (t & 3) * 16;
  const float* s = src + ((size_t)b * CC + cb + cl) * NN + nb + n0;
  f32x4 v0 = *(const f32x4*)(s);
  f32x4 v1 = *(const f32x4*)(s + 4);
  f32x4 v2 = *(const f32x4*)(s + 8);
  f32x4 v3 = *(const f32x4*)(s + 12);
#pragma unroll
  for (int j = 0; j < 4; ++j) {
    tile[cl][n0 + j] = v0[j];
    tile[cl][n0 + 4 + j] = v1[j];
    tile[cl][n0 + 8 + j] = v2[j];
    tile[cl][n0 + 12 + j] = v3[j];
  }
  __syncthreads();
  int nl = t >> 2, c0 = (t & 3) * 16;
  unsigned short* d = dst + ((size_t)b * NN + nb + nl) * CC + cb + c0;
  alignas(16) unsigned short tmp[16];
#pragma unroll
  for (int j = 0; j < 16; ++j) tmp[j] = f2bf(tile[c0 + j][nl]);
  *(bf16x8*)(d) = *(const bf16x8*)(tmp);
  *(bf16x8*)(d + 8) = *(const bf16x8*)(tmp + 8);
}

// ---------------------------------------------------------------------------
// Kernel 3: projections. Q pre-scaled by 0.125*log2(e) (exp2-domain softmax).
// ---------------------------------------------------------------------------
__global__ __launch_bounds__(256) void proj_kernel(
    const unsigned short* __restrict__ Xt0, const unsigned short* __restrict__ Xt1,
    const unsigned short* __restrict__ Xt2,
    const unsigned short* __restrict__ W1, const unsigned short* __restrict__ W2,
    const unsigned short* __restrict__ WV,
    const float* __restrict__ B1, const float* __restrict__ B2, const float* __restrict__ BV,
    unsigned short* __restrict__ Qb, unsigned short* __restrict__ Kb,
    unsigned short* __restrict__ Vt)
{
  int nt = blockIdx.x;
  int mat = blockIdx.y;
  int b = blockIdx.z;
  const unsigned short* X =
      (mat == 0 ? Xt1 : (mat == 1 ? Xt2 : Xt0)) + (size_t)b * NN * CC;
  const unsigned short* W = mat == 0 ? W1 : (mat == 1 ? W2 : WV);
  const float* Bi = mat == 0 ? B1 : (mat == 1 ? B2 : BV);
  int w = threadIdx.x >> 6, lane = threadIdx.x & 63;
  int lhi = lane >> 4, llo = lane & 15;
  int ob = w * 32;

  f32x4 acc[2][4] = {};
#pragma unroll
  for (int kc = 0; kc < 8; ++kc) {
    bf16x8 af[2], bfr[4];
#pragma unroll
    for (int ot = 0; ot < 2; ++ot)
      af[ot] = *(const bf16x8*)(W + (size_t)(ob + ot * 16 + llo) * CC + kc * 32 + lhi * 8);
#pragma unroll
    for (int nn = 0; nn < 4; ++nn)
      bfr[nn] = *(const bf16x8*)(X + ((size_t)nt * 64 + nn * 16 + llo) * CC + kc * 32 + lhi * 8);
#pragma unroll
    for (int ot = 0; ot < 2; ++ot)
#pragma unroll
      for (int nn = 0; nn < 4; ++nn)
        acc[ot][nn] = MFMA16(af[ot], bfr[nn], acc[ot][nn]);
  }

#pragma unroll
  for (int ot = 0; ot < 2; ++ot)
#pragma unroll
    for (int nn = 0; nn < 4; ++nn)
#pragma unroll
      for (int r = 0; r < 4; ++r) {
        int o = ob + ot * 16 + lhi * 4 + r;
        int n = nt * 64 + nn * 16 + llo;
        float val = acc[ot][nn][r] + Bi[o];
        if (mat < 2) {
          int blk = o >> 5;              // 0:K a0  1:Q a0  2:K a1  3:Q a1
          int aa = blk >> 1;
          int d = (o & 31) + mat * 32;
          if (blk & 1) val *= 0.18033688011f;   // 0.125 * log2(e)
          unsigned short* dstp = (blk & 1) ? Qb : Kb;
          dstp[((size_t)(b * 2 + aa) * NN + n) * DD + d] = f2bf(val);
        } else {
          int aa = o >> 6, d = o & 63;
          Vt[((size_t)(b * 2 + aa) * DD + d) * NN + n] = f2bf(val);
        }
      }
}

// ---------------------------------------------------------------------------
// Kernel 4: flash attention, swapped-QK^T, R8-verified per-wave structure
// (32 q-rows/wave, exp2 softmax, cvt_pk, defer-rescale), 8 waves/block:
// 2 wq (32q each) x 4 wk (1024-k quarters). Single-buffered per-quarter K/V
// (4 x 16KB = 64KB) -> 2 blocks/CU = 16 waves/CU. 16 iters/wave.
// __launch_bounds__(512,2): R12's (512,4) capped VGPR at 128 and the
// allocator spilled catastrophically (VGPR=64, WRITE_SIZE 205MB); cap 256
// lets the natural ~88-VGPR allocation stand (R7->R8 lesson reapplied).
// ---------------------------------------------------------------------------
__global__ __launch_bounds__(512, 2) void attn_kernel(
    const unsigned short* __restrict__ Qb, const unsigned short* __restrict__ Kb,
    const unsigned short* __restrict__ Vt, unsigned short* __restrict__ Ob)
{
  int qt = blockIdx.x;                  // 64-q tile
  int a = blockIdx.y;
  int b = blockIdx.z;
  int ba = b * 2 + a;
  int tid = threadIdx.x;
  int w = tid >> 6;                     // 0..7
  int lane = tid & 63;
  int lhi = lane >> 4, llo = lane & 15;
  int wq = w & 1, wk = w >> 1;          // wk in 0..3: 1024-k quarter

  __shared__ char lds[65536];           // [wk][ K 8KB | V 8KB ] single-buf

  char* Ks = lds + wk * 16384;
  char* Vs = Ks + 8192;

  // Q as B-operand: qf[qh][h], lane holds Q[q = qh*16+llo][d = h*32+lhi*8..+8]
  const unsigned short* Qg = Qb + ((size_t)ba * NN + qt * 64 + wq * 32) * DD;
  bf16x8 qf[2][2];
#pragma unroll
  for (int qh = 0; qh < 2; ++qh)
#pragma unroll
    for (int h = 0; h < 2; ++h)
      qf[qh][h] = *(const bf16x8*)(Qg + (size_t)(qh * 16 + llo) * DD + h * 32 + lhi * 8);

  const unsigned short* Kg = Kb + ((size_t)ba * NN + wk * 1024) * DD;
  const unsigned short* Vg = Vt + (size_t)ba * DD * NN + wk * 1024;

  f32x4 oacc[2][4] = {};
  float m[2] = {-1e30f, -1e30f}, lsum[2] = {0.f, 0.f};

  // staging: the 128 threads of quarter wk (waves 2wk, 2wk+1) stage its tile
  int t7 = tid & 127;
  int sr8 = t7 >> 3, scol = t7 & 7;

  f32x4 kreg[4], vreg[4];
#define STAGE_LOAD(IT)                                                        \
  {                                                                           \
    int kb_ = (IT) * 64;                                                      \
    _Pragma("unroll") for (int i = 0; i < 4; ++i) {                           \
      int row = i * 16 + sr8;                                                 \
      kreg[i] = *(const f32x4*)(Kg + (size_t)(kb_ + row) * DD + scol * 8);    \
      vreg[i] = *(const f32x4*)(Vg + (size_t)row * NN + kb_ + scol * 8);      \
    }                                                                         \
  }
#define STAGE_WRITE()                                                        \
  {                                                                           \
    _Pragma("unroll") for (int i = 0; i < 4; ++i) {                           \
      int row = i * 16 + sr8;                                                 \
      int swz = (scol * 16) ^ swz16(row);                                     \
      *(f32x4*)(Ks + row * 128 + swz) = kreg[i];                              \
      *(f32x4*)(Vs + row * 128 + swz) = vreg[i];                              \
    }                                                                         \
  }

  STAGE_LOAD(0);
  STAGE_WRITE();
  __syncthreads();

  for (int it = 0; it < 16; ++it) {
    if (it < 15) STAGE_LOAD(it + 1);

    // S^T = K_perm @ Q (K fragment shared by both qh)
    f32x4 s[2][4] = {};
    __builtin_amdgcn_s_setprio(1);
#pragma unroll
    for (int t = 0; t < 4; ++t) {
      int krow = (t & 1) * 32 + ((llo >> 2) << 3) + ((t >> 1) << 2) + (llo & 3);
      int ksz = swz16(krow);
      const char* kp = Ks + krow * 128;
      bf16x8 k0 = *(const bf16x8*)(kp + ((lhi * 16) ^ ksz));
      bf16x8 k1 = *(const bf16x8*)(kp + ((64 + lhi * 16) ^ ksz));
      s[0][t] = MFMA16(k0, qf[0][0], s[0][t]);
      s[0][t] = MFMA16(k1, qf[0][1], s[0][t]);
      s[1][t] = MFMA16(k0, qf[1][0], s[1][t]);
      s[1][t] = MFMA16(k1, qf[1][1], s[1][t]);
    }
    __builtin_amdgcn_s_setprio(0);

    // online softmax per qh (exp2 domain; lane owns one q per qh)
    union { unsigned int u[4]; bf16x8 v; } F0[2], F1[2];
#pragma unroll
    for (int qh = 0; qh < 2; ++qh) {
      float t0 = fmaxf(fmaxf(s[qh][0][0], s[qh][0][1]), fmaxf(s[qh][0][2], s[qh][0][3]));
      float t1 = fmaxf(fmaxf(s[qh][1][0], s[qh][1][1]), fmaxf(s[qh][1][2], s[qh][1][3]));
      float t2 = fmaxf(fmaxf(s[qh][2][0], s[qh][2][1]), fmaxf(s[qh][2][2], s[qh][2][3]));
      float t3 = fmaxf(fmaxf(s[qh][3][0], s[qh][3][1]), fmaxf(s[qh][3][2], s[qh][3][3]));
      float pm = fmaxf(fmaxf(t0, t1), fmaxf(t2, t3));
      pm = fmaxf(pm, __shfl_xor(pm, 16));
      pm = fmaxf(pm, __shfl_xor(pm, 32));
      if (__any(pm > m[qh])) {   // exact skip: pm<=m everywhere => al==1
        float mn = fmaxf(m[qh], pm);
        float al = __builtin_amdgcn_exp2f(m[qh] - mn);
        m[qh] = mn;
        lsum[qh] *= al;
#pragma unroll
        for (int dt = 0; dt < 4; ++dt)
#pragma unroll
          for (int r = 0; r < 4; ++r) oacc[qh][dt][r] *= al;
      }
#pragma unroll
      for (int t = 0; t < 4; ++t)
#pragma unroll
        for (int r = 0; r < 4; ++r)
          s[qh][t][r] = __builtin_amdgcn_exp2f(s[qh][t][r] - m[qh]);
      float p0 = (s[qh][0][0] + s[qh][0][1]) + (s[qh][0][2] + s[qh][0][3]);
      float p1 = (s[qh][1][0] + s[qh][1][1]) + (s[qh][1][2] + s[qh][1][3]);
      float p2 = (s[qh][2][0] + s[qh][2][1]) + (s[qh][2][2] + s[qh][2][3]);
      float p3 = (s[qh][3][0] + s[qh][3][1]) + (s[qh][3][2] + s[qh][3][3]);
      lsum[qh] += (p0 + p1) + (p2 + p3);

      F0[qh].u[0] = cvtpk(s[qh][0][0], s[qh][0][1]); F0[qh].u[1] = cvtpk(s[qh][0][2], s[qh][0][3]);
      F0[qh].u[2] = cvtpk(s[qh][2][0], s[qh][2][1]); F0[qh].u[3] = cvtpk(s[qh][2][2], s[qh][2][3]);
      F1[qh].u[0] = cvtpk(s[qh][1][0], s[qh][1][1]); F1[qh].u[1] = cvtpk(s[qh][1][2], s[qh][1][3]);
      F1[qh].u[2] = cvtpk(s[qh][3][0], s[qh][3][1]); F1[qh].u[3] = cvtpk(s[qh][3][2], s[qh][3][3]);
    }

    // O^T += V^T @ P^T (V fragment shared by both qh)
    __builtin_amdgcn_s_setprio(1);
#pragma unroll
    for (int dt = 0; dt < 4; ++dt) {
      int vrow = dt * 16 + llo;
      int vsz = swz16(vrow);
      const char* vp = Vs + vrow * 128;
      bf16x8 v0 = *(const bf16x8*)(vp + ((lhi * 16) ^ vsz));
      bf16x8 v1 = *(const bf16x8*)(vp + ((64 + lhi * 16) ^ vsz));
      oacc[0][dt] = MFMA16(v0, F0[0].v, oacc[0][dt]);
      oacc[0][dt] = MFMA16(v1, F1[0].v, oacc[0][dt]);
      oacc[1][dt] = MFMA16(v0, F0[1].v, oacc[1][dt]);
      oacc[1][dt] = MFMA16(v1, F1[1].v, oacc[1][dt]);
    }
    __builtin_amdgcn_s_setprio(0);

    __syncthreads();
    if (it < 15) STAGE_WRITE();
    __syncthreads();
  }

  // full row sums across the 4 lanes sharing each q
#pragma unroll
  for (int qh = 0; qh < 2; ++qh) {
    lsum[qh] += __shfl_xor(lsum[qh], 16);
    lsum[qh] += __shfl_xor(lsum[qh], 32);
  }

  // 4-way merge: wk 1..3 publish partials (stride-65 rows); wk0 combines.
  float* mO = (float*)lds;                 // [(wk-1)*64 + ql][65]
  float* mM = (float*)(lds + 50176);       // [3][64]
  float* mL = mM + 192;
  if (wk != 0) {
#pragma unroll
    for (int qh = 0; qh < 2; ++qh) {
      int ql = wq * 32 + qh * 16 + llo;
      int rowi = (wk - 1) * 64 + ql;
#pragma unroll
      for (int dt = 0; dt < 4; ++dt)
#pragma unroll
        for (int r = 0; r < 4; ++r)
          mO[rowi * 65 + dt * 16 + lhi * 4 + r] = oacc[qh][dt][r];
      if (lhi == 0) { mM[rowi] = m[qh]; mL[rowi] = lsum[qh]; }
    }
  }
  __syncthreads();
  if (wk == 0) {
#pragma unroll
    for (int qh = 0; qh < 2; ++qh) {
      int ql = wq * 32 + qh * 16 + llo;
      float mf = m[qh];
      float mp[3], lp[3];
#pragma unroll
      for (int p = 0; p < 3; ++p) {
        mp[p] = mM[p * 64 + ql];
        lp[p] = mL[p * 64 + ql];
        mf = fmaxf(mf, mp[p]);
      }
      float e0 = __builtin_amdgcn_exp2f(m[qh] - mf);
      float L = lsum[qh] * e0;
      float ep[3];
#pragma unroll
      for (int p = 0; p < 3; ++p) {
        ep[p] = __builtin_amdgcn_exp2f(mp[p] - mf);
        L += lp[p] * ep[p];
      }
      float inv = 1.f / L;
      int qglob = qt * 64 + ql;
      unsigned int* dst = (unsigned int*)(Ob + ((size_t)b * NN + qglob) * 128 + a * 64);
#pragma unroll
      for (int dt = 0; dt < 4; ++dt) {
        int d0 = dt * 16 + lhi * 4;
        float v[4];
#pragma unroll
        for (int r = 0; r < 4; ++r) {
          float acc = oacc[qh][dt][r] * e0;
#pragma unroll
          for (int p = 0; p < 3; ++p) acc += mO[(p * 64 + ql) * 65 + d0 + r] * ep[p];
          v[r] = acc * inv;
        }
        dst[dt * 8 + lhi * 2] = pk2(v[0], v[1]);
        dst[dt * 8 + lhi * 2 + 1] = pk2(v[2], v[3]);
      }
    }
  }
}

// ---------------------------------------------------------------------------
// Kernel 5: OUT[b,c,n] = sum_d WO[c,d]*O[b,n,d] + BO[c] + x[b,c,n]
// ---------------------------------------------------------------------------
__global__ __launch_bounds__(256) void out_kernel(
    const unsigned short* __restrict__ Ob, const unsigned short* __restrict__ WO,
    const float* __restrict__ BO, const float* __restrict__ x,
    float* __restrict__ out)
{
  int nt = blockIdx.x;
  int ct = blockIdx.y;
  int b = blockIdx.z;
  int w = threadIdx.x >> 6, lane = threadIdx.x & 63;
  int lhi = lane >> 4, llo = lane & 15;
  int cb = ct * 64 + w * 16;

  f32x4 acc[4] = {};
#pragma unroll
  for (int kc = 0; kc < 4; ++kc) {
    bf16x8 af = *(const bf16x8*)(WO + (size_t)(cb + llo) * 128 + kc * 32 + lhi * 8);
#pragma unroll
    for (int nn = 0; nn < 4; ++nn) {
      bf16x8 bfr = *(const bf16x8*)(Ob + ((size_t)b * NN + nt * 64 + nn * 16 + llo) * 128 + kc * 32 + lhi * 8);
      acc[nn] = MFMA16(af, bfr, acc[nn]);
    }
  }
#pragma unroll
  for (int nn = 0; nn < 4; ++nn)
#pragma unroll
    for (int r = 0; r < 4; ++r) {
      int c = cb + lhi * 4 + r;
      int n = nt * 64 + nn * 16 + llo;
      size_t idx = ((size_t)b * CC + c) * NN + n;
      out[idx] = acc[nn][r] + BO[c] + x[idx];
    }
}

// ---------------------------------------------------------------------------
extern "C" void kernel_launch(void* const* d_in, const int* in_sizes, int n_in,
                              void* d_out, int out_size, void* d_ws, size_t ws_size,
                              hipStream_t stream) {
  const float* x = (const float*)d_in[0];
  const float* x1 = (const float*)d_in[1];
  const float* x2 = (const float*)d_in[2];
  const float* bn1_g = (const float*)d_in[3];
  const float* bn1_b = (const float*)d_in[4];
  const float* bn1_m = (const float*)d_in[5];
  const float* bn1_v = (const float*)d_in[6];
  const float* bn2_g = (const float*)d_in[7];
  const float* bn2_b = (const float*)d_in[8];
  const float* bn2_m = (const float*)d_in[9];
  const float* bn2_v = (const float*)d_in[10];
  const float* kq1_w = (const float*)d_in[11];
  const float* kq1_b = (const float*)d_in[12];
  const float* kq2_w = (const float*)d_in[13];
  const float* kq2_b = (const float*)d_in[14];
  const float* v_w = (const float*)d_in[15];
  const float* v_b = (const float*)d_in[16];
  const float* out_w = (const float*)d_in[17];
  const float* out_b = (const float*)d_in[18];
  const float* bnl_g = (const float*)d_in[19];
  const float* bnl_b = (const float*)d_in[20];
  const float* bnl_m = (const float*)d_in[21];
  const float* bnl_v = (const float*)d_in[22];
  const float* w_scale = (const float*)d_in[23];

  char* ws = (char*)d_ws;
  const size_t XT_SZ = (size_t)NB * NN * CC * 2;        // 8 MB each
  const size_t QKV_SZ = (size_t)NB * 2 * NN * DD * 2;   // 4 MB each
  size_t off = 0;
  unsigned short* XT0 = (unsigned short*)(ws + off); off += XT_SZ;
  unsigned short* XT1 = (unsigned short*)(ws + off); off += XT_SZ;
  unsigned short* XT2 = (unsigned short*)(ws + off); off += XT_SZ;
  unsigned short* Qb = (unsigned short*)(ws + off); off += QKV_SZ;
  unsigned short* Kb = (unsigned short*)(ws + off); off += QKV_SZ;
  unsigned short* Vt = (unsigned short*)(ws + off); off += QKV_SZ;
  unsigned short* Ob = (unsigned short*)(ws + off); off += (size_t)NB * NN * 128 * 2;
  unsigned short* W1 = (unsigned short*)(ws + off); off += 128 * CC * 2;
  unsigned short* W2 = (unsigned short*)(ws + off); off += 128 * CC * 2;
  unsigned short* WV = (unsigned short*)(ws + off); off += 128 * CC * 2;
  unsigned short* WO = (unsigned short*)(ws + off); off += CC * 128 * 2;
  float* B1 = (float*)(ws + off); off += 512;
  float* B2 = (float*)(ws + off); off += 512;
  float* BV = (float*)(ws + off); off += 512;
  float* BO = (float*)(ws + off); off += 1024;
  if (ws_size < off) return;  // loud failure: output stays poisoned

  prep_kernel<<<16, 256, 0, stream>>>(
      kq1_w, kq1_b, kq2_w, kq2_b, v_w, v_b, out_w, out_b,
      bn1_g, bn1_b, bn1_m, bn1_v, bn2_g, bn2_b, bn2_m, bn2_v,
      bnl_g, bnl_b, bnl_m, bnl_v, w_scale,
      W1, W2, WV, WO, B1, B2, BV, BO);

  conv_kernel<<<dim3(64, 4, 12), 256, 0, stream>>>(x, x1, x2, XT0, XT1, XT2);

  proj_kernel<<<dim3(64, 3, 4), 256, 0, stream>>>(
      XT0, XT1, XT2, W1, W2, WV, B1, B2, BV, Qb, Kb, Vt);

  attn_kernel<<<dim3(64, 2, 4), 512, 0, stream>>>(Qb, Kb, Vt, Ob);

  out_kernel<<<dim3(64, 4, 4), 256, 0, stream>>>(Ob, WO, BO, x, (float*)d_out);
}

// Round 14
// 107.017 us; speedup vs baseline: 1.6821x; 1.2472x over previous
//
#include <hip/hip_runtime.h>

typedef short bf16x8 __attribute__((ext_vector_type(8)));
typedef float f32x4 __attribute__((ext_vector_type(4)));
typedef float f32x2 __attribute__((ext_vector_type(2)));
typedef unsigned short u16x4 __attribute__((ext_vector_type(4)));
typedef unsigned short u16x2 __attribute__((ext_vector_type(2)));

#define MFMA16(A, B, C) __builtin_amdgcn_mfma_f32_16x16x32_bf16((A), (B), (C), 0, 0, 0)

static constexpr int NB = 4;       // batch
static constexpr int CC = 256;     // channels (INC1 == INC2)
static constexpr int NN = 4096;    // H*W
static constexpr int DD = 64;      // head dim

__device__ __forceinline__ unsigned short f2bf(float f) {
  unsigned int u = __builtin_bit_cast(unsigned int, f);
  u += 0x7fffu + ((u >> 16) & 1u);
  return (unsigned short)(u >> 16);
}

__device__ __forceinline__ unsigned int pk2(float lo, float hi) {
  return (unsigned int)f2bf(lo) | ((unsigned int)f2bf(hi) << 16);
}

// T12 recipe: packed f32->bf16x2 convert (RNE), 1 instruction.
__device__ __forceinline__ unsigned int cvtpk(float lo, float hi) {
  unsigned int r;
  asm("v_cvt_pk_bf16_f32 %0, %1, %2" : "=v"(r) : "v"(lo), "v"(hi));
  return r;
}

// LDS 16B-slot swizzle (R5-verified)
__device__ __forceinline__ int swz16(int row) {
  return ((row & 3) | ((((row >> 2) ^ (row >> 3)) & 1) << 2)) << 4;
}

// ---------------------------------------------------------------------------
// Kernel 1: fold BN into projection weights. Grid 16 (R11-verified).
// ---------------------------------------------------------------------------
__global__ __launch_bounds__(256) void prep_kernel(
    const float* __restrict__ kq1_w, const float* __restrict__ kq1_b,
    const float* __restrict__ kq2_w, const float* __restrict__ kq2_b,
    const float* __restrict__ v_w,   const float* __restrict__ v_b,
    const float* __restrict__ out_w, const float* __restrict__ out_b,
    const float* __restrict__ bn1_g, const float* __restrict__ bn1_b,
    const float* __restrict__ bn1_m, const float* __restrict__ bn1_v,
    const float* __restrict__ bn2_g, const float* __restrict__ bn2_b,
    const float* __restrict__ bn2_m, const float* __restrict__ bn2_v,
    const float* __restrict__ bnl_g, const float* __restrict__ bnl_b,
    const float* __restrict__ bnl_m, const float* __restrict__ bnl_v,
    const float* __restrict__ w_scale,
    unsigned short* __restrict__ W1, unsigned short* __restrict__ W2,
    unsigned short* __restrict__ WV, unsigned short* __restrict__ WO,
    float* __restrict__ B1, float* __restrict__ B2,
    float* __restrict__ BV, float* __restrict__ BO)
{
  int blk = blockIdx.x;
  int tid = threadIdx.x;
  int w = tid >> 6, lane = tid & 63;
  if (blk < 12) {
    int mat = blk >> 2, rg = blk & 3;
    const float* Wsrc = mat == 0 ? kq1_w : (mat == 1 ? kq2_w : v_w);
    const float* bsrc = mat == 0 ? kq1_b : (mat == 1 ? kq2_b : v_b);
    unsigned short* Wdst = mat == 0 ? W1 : (mat == 1 ? W2 : WV);
    float* Bdst = mat == 0 ? B1 : (mat == 1 ? B2 : BV);
    __shared__ float s_lds[256], o_lds[256];
    if (mat == 0) {
      float s = bn1_g[tid] * rsqrtf(bn1_v[tid] + 1e-5f);
      s_lds[tid] = s;
      o_lds[tid] = bn1_b[tid] - bn1_m[tid] * s;
    } else if (mat == 1) {
      float s = bn2_g[tid] * rsqrtf(bn2_v[tid] + 1e-5f);
      s_lds[tid] = s;
      o_lds[tid] = bn2_b[tid] - bn2_m[tid] * s;
    } else {
      s_lds[tid] = 1.f;
      o_lds[tid] = 0.f;
    }
    __syncthreads();
    int c = lane * 4;
    for (int row = rg * 32 + w; row < rg * 32 + 32; row += 4) {
      f32x4 wv = *(const f32x4*)(Wsrc + row * CC + c);
      u16x4 o;
      float bacc = 0.f;
#pragma unroll
      for (int j = 0; j < 4; ++j) {
        o[j] = f2bf(wv[j] * s_lds[c + j]);
        bacc += wv[j] * o_lds[c + j];
      }
      *(u16x4*)(Wdst + row * CC + c) = o;
#pragma unroll
      for (int off = 1; off < 64; off <<= 1) bacc += __shfl_xor(bacc, off);
      if (lane == 0) Bdst[row] = bsrc[row] + bacc;
    }
  } else {
    int rg = blk - 12;
    float ws = w_scale[0];
    if (rg == 0) {
      float s = bnl_g[tid] * rsqrtf(bnl_v[tid] + 1e-5f);
      BO[tid] = ws * (out_b[tid] * s + bnl_b[tid] - bnl_m[tid] * s);
    }
    int d = lane * 2;
    for (int row = rg * 64 + w; row < rg * 64 + 64; row += 4) {
      float s = ws * bnl_g[row] * rsqrtf(bnl_v[row] + 1e-5f);
      f32x2 wv = *(const f32x2*)(out_w + row * 128 + d);
      u16x2 o;
      o[0] = f2bf(s * wv[0]);
      o[1] = f2bf(s * wv[1]);
      *(u16x2*)(WO + row * 128 + d) = o;
    }
  }
}

// ---------------------------------------------------------------------------
// Kernel 2: FUSED transpose + projection. Per block (nt, mat, b): stage 4x
// 64c x 64n f32 sub-tiles via conv-verified ftile transpose, pack bf16 into a
// swizzled LDS tile (byte ^= (n&7)<<4), then R11-verified MFMA loop with
// B-fragments from LDS. Eliminates the 72MB XT round-trip entirely.
// Q pre-scaled by 0.125*log2(e) (exp2-domain softmax).
// ---------------------------------------------------------------------------
__global__ __launch_bounds__(256) void proj_kernel(
    const float* __restrict__ x, const float* __restrict__ x1,
    const float* __restrict__ x2,
    const unsigned short* __restrict__ W1, const unsigned short* __restrict__ W2,
    const unsigned short* __restrict__ WV,
    const float* __restrict__ B1, const float* __restrict__ B2, const float* __restrict__ BV,
    unsigned short* __restrict__ Qb, unsigned short* __restrict__ Kb,
    unsigned short* __restrict__ Vt)
{
  int nt = blockIdx.x;
  int mat = blockIdx.y;
  int b = blockIdx.z;
  const float* src = mat == 0 ? x1 : (mat == 1 ? x2 : x);
  const unsigned short* W = mat == 0 ? W1 : (mat == 1 ? W2 : WV);
  const float* Bi = mat == 0 ? B1 : (mat == 1 ? B2 : BV);
  int t = threadIdx.x;
  int w = t >> 6, lane = t & 63;
  int lhi = lane >> 4, llo = lane & 15;

  __shared__ float ftile[64][65];                 // f32 transpose staging
  __shared__ unsigned short xt[64 * 256];         // bf16 (n,c) tile, swizzled

  // ---- stage: 4 c-subtiles of 64c x 64n ----
  int cl = t >> 2, n0q = (t & 3) * 16;            // global-read mapping
  int nl = t >> 2, c0 = (t & 3) * 16;             // pack mapping
#pragma unroll
  for (int cb = 0; cb < 4; ++cb) {
    const float* s = src + ((size_t)b * CC + cb * 64 + cl) * NN + nt * 64 + n0q;
    f32x4 v0 = *(const f32x4*)(s);
    f32x4 v1 = *(const f32x4*)(s + 4);
    f32x4 v2 = *(const f32x4*)(s + 8);
    f32x4 v3 = *(const f32x4*)(s + 12);
    if (cb) __syncthreads();                      // prev pack done
#pragma unroll
    for (int j = 0; j < 4; ++j) {
      ftile[cl][n0q + j] = v0[j];
      ftile[cl][n0q + 4 + j] = v1[j];
      ftile[cl][n0q + 8 + j] = v2[j];
      ftile[cl][n0q + 12 + j] = v3[j];
    }
    __syncthreads();
    alignas(16) unsigned short tmp[16];
#pragma unroll
    for (int j = 0; j < 16; ++j) tmp[j] = f2bf(ftile[c0 + j][nl]);
    int rowswz = (nl & 7) << 4;
    char* base = (char*)xt + nl * 512;
    *(bf16x8*)(base + ((cb * 128 + c0 * 2) ^ rowswz)) = *(const bf16x8*)(tmp);
    *(bf16x8*)(base + ((cb * 128 + c0 * 2 + 16) ^ rowswz)) = *(const bf16x8*)(tmp + 8);
  }
  __syncthreads();

  // ---- MFMA: C(128 x 64n) = Weff(128x256) @ xt(n,256)^T ----
  int ob = w * 32;
  f32x4 acc[2][4] = {};
#pragma unroll
  for (int kc = 0; kc < 8; ++kc) {
    bf16x8 af[2], bfr[4];
#pragma unroll
    for (int ot = 0; ot < 2; ++ot)
      af[ot] = *(const bf16x8*)(W + (size_t)(ob + ot * 16 + llo) * CC + kc * 32 + lhi * 8);
#pragma unroll
    for (int nn = 0; nn < 4; ++nn) {
      int n = nn * 16 + llo;
      bfr[nn] = *(const bf16x8*)((char*)xt + n * 512 + ((kc * 64 + lhi * 16) ^ ((n & 7) << 4)));
    }
#pragma unroll
    for (int ot = 0; ot < 2; ++ot)
#pragma unroll
      for (int nn = 0; nn < 4; ++nn)
        acc[ot][nn] = MFMA16(af[ot], bfr[nn], acc[ot][nn]);
  }

#pragma unroll
  for (int ot = 0; ot < 2; ++ot)
#pragma unroll
    for (int nn = 0; nn < 4; ++nn)
#pragma unroll
      for (int r = 0; r < 4; ++r) {
        int o = ob + ot * 16 + lhi * 4 + r;
        int n = nt * 64 + nn * 16 + llo;
        float val = acc[ot][nn][r] + Bi[o];
        if (mat < 2) {
          int blk = o >> 5;              // 0:K a0  1:Q a0  2:K a1  3:Q a1
          int aa = blk >> 1;
          int d = (o & 31) + mat * 32;
          if (blk & 1) val *= 0.18033688011f;   // 0.125 * log2(e)
          unsigned short* dstp = (blk & 1) ? Qb : Kb;
          dstp[((size_t)(b * 2 + aa) * NN + n) * DD + d] = f2bf(val);
        } else {
          int aa = o >> 6, d = o & 63;
          Vt[((size_t)(b * 2 + aa) * DD + d) * NN + n] = f2bf(val);
        }
      }
}

// ---------------------------------------------------------------------------
// Kernel 3: flash attention — R11-verified best (swapped-QK^T, 32 q/wave,
// exp2 softmax, cvt_pk, defer-rescale, K/V double-buffer, 1 barrier/iter).
// ---------------------------------------------------------------------------
__global__ __launch_bounds__(256, 2) void attn_kernel(
    const unsigned short* __restrict__ Qb, const unsigned short* __restrict__ Kb,
    const unsigned short* __restrict__ Vt, unsigned short* __restrict__ Ob)
{
  int qt = blockIdx.x;                  // 64-q tile
  int a = blockIdx.y;
  int b = blockIdx.z;
  int ba = b * 2 + a;
  int tid = threadIdx.x;
  int w = tid >> 6;
  int lane = tid & 63;
  int lhi = lane >> 4, llo = lane & 15;
  int wq = w & 1, wk = w >> 1;

  __shared__ char lds[65536];           // [wk][buf][ K 8KB | V 8KB ]

  const unsigned short* Qg = Qb + ((size_t)ba * NN + qt * 64 + wq * 32) * DD;
  bf16x8 qf[2][2];
#pragma unroll
  for (int qh = 0; qh < 2; ++qh)
#pragma unroll
    for (int h = 0; h < 2; ++h)
      qf[qh][h] = *(const bf16x8*)(Qg + (size_t)(qh * 16 + llo) * DD + h * 32 + lhi * 8);

  const unsigned short* Kg = Kb + ((size_t)ba * NN + wk * 2048) * DD;
  const unsigned short* Vg = Vt + (size_t)ba * DD * NN + wk * 2048;

  f32x4 oacc[2][4] = {};
  float m[2] = {-1e30f, -1e30f}, lsum[2] = {0.f, 0.f};

  int t7 = tid & 127;
  int sr8 = t7 >> 3, scol = t7 & 7;

  f32x4 kreg[4], vreg[4];
#define STAGE_LOAD(IT)                                                        \
  {                                                                           \
    int kb_ = (IT) * 64;                                                      \
    _Pragma("unroll") for (int i = 0; i < 4; ++i) {                           \
      int row = i * 16 + sr8;                                                 \
      kreg[i] = *(const f32x4*)(Kg + (size_t)(kb_ + row) * DD + scol * 8);    \
      vreg[i] = *(const f32x4*)(Vg + (size_t)row * NN + kb_ + scol * 8);      \
    }                                                                         \
  }
#define STAGE_WRITE(BUF)                                                      \
  {                                                                           \
    char* base_ = lds + wk * 32768 + (BUF) * 16384;                           \
    _Pragma("unroll") for (int i = 0; i < 4; ++i) {                           \
      int row = i * 16 + sr8;                                                 \
      int swz = (scol * 16) ^ swz16(row);                                     \
      *(f32x4*)(base_ + row * 128 + swz) = kreg[i];                           \
      *(f32x4*)(base_ + 8192 + row * 128 + swz) = vreg[i];                    \
    }                                                                         \
  }

  STAGE_LOAD(0);
  STAGE_WRITE(0);
  __syncthreads();

  int cur = 0;
  for (int it = 0; it < 32; ++it) {
    if (it < 31) STAGE_LOAD(it + 1);
    const char* Ks = lds + wk * 32768 + cur * 16384;
    const char* Vs = Ks + 8192;

    // S^T = K_perm @ Q (K fragment shared by both qh)
    f32x4 s[2][4] = {};
    __builtin_amdgcn_s_setprio(1);
#pragma unroll
    for (int t = 0; t < 4; ++t) {
      int krow = (t & 1) * 32 + ((llo >> 2) << 3) + ((t >> 1) << 2) + (llo & 3);
      int ksz = swz16(krow);
      const char* kp = Ks + krow * 128;
      bf16x8 k0 = *(const bf16x8*)(kp + ((lhi * 16) ^ ksz));
      bf16x8 k1 = *(const bf16x8*)(kp + ((64 + lhi * 16) ^ ksz));
      s[0][t] = MFMA16(k0, qf[0][0], s[0][t]);
      s[0][t] = MFMA16(k1, qf[0][1], s[0][t]);
      s[1][t] = MFMA16(k0, qf[1][0], s[1][t]);
      s[1][t] = MFMA16(k1, qf[1][1], s[1][t]);
    }
    __builtin_amdgcn_s_setprio(0);

    // online softmax per qh (exp2 domain; lane owns one q per qh)
    union { unsigned int u[4]; bf16x8 v; } F0[2], F1[2];
#pragma unroll
    for (int qh = 0; qh < 2; ++qh) {
      float t0 = fmaxf(fmaxf(s[qh][0][0], s[qh][0][1]), fmaxf(s[qh][0][2], s[qh][0][3]));
      float t1 = fmaxf(fmaxf(s[qh][1][0], s[qh][1][1]), fmaxf(s[qh][1][2], s[qh][1][3]));
      float t2 = fmaxf(fmaxf(s[qh][2][0], s[qh][2][1]), fmaxf(s[qh][2][2], s[qh][2][3]));
      float t3 = fmaxf(fmaxf(s[qh][3][0], s[qh][3][1]), fmaxf(s[qh][3][2], s[qh][3][3]));
      float pm = fmaxf(fmaxf(t0, t1), fmaxf(t2, t3));
      pm = fmaxf(pm, __shfl_xor(pm, 16));
      pm = fmaxf(pm, __shfl_xor(pm, 32));
      if (__any(pm > m[qh])) {   // exact skip: pm<=m everywhere => al==1
        float mn = fmaxf(m[qh], pm);
        float al = __builtin_amdgcn_exp2f(m[qh] - mn);
        m[qh] = mn;
        lsum[qh] *= al;
#pragma unroll
        for (int dt = 0; dt < 4; ++dt)
#pragma unroll
          for (int r = 0; r < 4; ++r) oacc[qh][dt][r] *= al;
      }
#pragma unroll
      for (int t = 0; t < 4; ++t)
#pragma unroll
        for (int r = 0; r < 4; ++r)
          s[qh][t][r] = __builtin_amdgcn_exp2f(s[qh][t][r] - m[qh]);
      float p0 = (s[qh][0][0] + s[qh][0][1]) + (s[qh][0][2] + s[qh][0][3]);
      float p1 = (s[qh][1][0] + s[qh][1][1]) + (s[qh][1][2] + s[qh][1][3]);
      float p2 = (s[qh][2][0] + s[qh][2][1]) + (s[qh][2][2] + s[qh][2][3]);
      float p3 = (s[qh][3][0] + s[qh][3][1]) + (s[qh][3][2] + s[qh][3][3]);
      lsum[qh] += (p0 + p1) + (p2 + p3);

      F0[qh].u[0] = cvtpk(s[qh][0][0], s[qh][0][1]); F0[qh].u[1] = cvtpk(s[qh][0][2], s[qh][0][3]);
      F0[qh].u[2] = cvtpk(s[qh][2][0], s[qh][2][1]); F0[qh].u[3] = cvtpk(s[qh][2][2], s[qh][2][3]);
      F1[qh].u[0] = cvtpk(s[qh][1][0], s[qh][1][1]); F1[qh].u[1] = cvtpk(s[qh][1][2], s[qh][1][3]);
      F1[qh].u[2] = cvtpk(s[qh][3][0], s[qh][3][1]); F1[qh].u[3] = cvtpk(s[qh][3][2], s[qh][3][3]);
    }

    // O^T += V^T @ P^T (V fragment shared by both qh)
    __builtin_amdgcn_s_setprio(1);
#pragma unroll
    for (int dt = 0; dt < 4; ++dt) {
      int vrow = dt * 16 + llo;
      int vsz = swz16(vrow);
      const char* vp = Vs + vrow * 128;
      bf16x8 v0 = *(const bf16x8*)(vp + ((lhi * 16) ^ vsz));
      bf16x8 v1 = *(const bf16x8*)(vp + ((64 + lhi * 16) ^ vsz));
      oacc[0][dt] = MFMA16(v0, F0[0].v, oacc[0][dt]);
      oacc[0][dt] = MFMA16(v1, F1[0].v, oacc[0][dt]);
      oacc[1][dt] = MFMA16(v0, F0[1].v, oacc[1][dt]);
      oacc[1][dt] = MFMA16(v1, F1[1].v, oacc[1][dt]);
    }
    __builtin_amdgcn_s_setprio(0);

    if (it < 31) STAGE_WRITE(cur ^ 1);  // other buffer: no pre-write drain
    __syncthreads();                    // publish writes + fence next iter
    cur ^= 1;
  }

#pragma unroll
  for (int qh = 0; qh < 2; ++qh) {
    lsum[qh] += __shfl_xor(lsum[qh], 16);
    lsum[qh] += __shfl_xor(lsum[qh], 32);
  }

  // merge the two wk-halves via LDS (stride 65)
  float* mO = (float*)lds;               // [64 q][65]
  float* mM = (float*)lds + 64 * 65;     // [64]
  float* mL = mM + 64;
  if (wk == 1) {
#pragma unroll
    for (int qh = 0; qh < 2; ++qh) {
      int ql = wq * 32 + qh * 16 + llo;
#pragma unroll
      for (int dt = 0; dt < 4; ++dt)
#pragma unroll
        for (int r = 0; r < 4; ++r)
          mO[ql * 65 + dt * 16 + lhi * 4 + r] = oacc[qh][dt][r];
      if (lhi == 0) { mM[ql] = m[qh]; mL[ql] = lsum[qh]; }
    }
  }
  __syncthreads();
  if (wk == 0) {
#pragma unroll
    for (int qh = 0; qh < 2; ++qh) {
      int ql = wq * 32 + qh * 16 + llo;
      float m2 = mM[ql], l2 = mL[ql];
      float mf = fmaxf(m[qh], m2);
      float e1 = __builtin_amdgcn_exp2f(m[qh] - mf);
      float e2 = __builtin_amdgcn_exp2f(m2 - mf);
      float inv = 1.f / (lsum[qh] * e1 + l2 * e2);
      int qglob = qt * 64 + ql;
      unsigned int* dst = (unsigned int*)(Ob + ((size_t)b * NN + qglob) * 128 + a * 64);
      const float* mOr = mO + ql * 65;
#pragma unroll
      for (int dt = 0; dt < 4; ++dt) {
        int d0 = dt * 16 + lhi * 4;
        float v0 = (oacc[qh][dt][0] * e1 + mOr[d0 + 0] * e2) * inv;
        float v1 = (oacc[qh][dt][1] * e1 + mOr[d0 + 1] * e2) * inv;
        float v2 = (oacc[qh][dt][2] * e1 + mOr[d0 + 2] * e2) * inv;
        float v3 = (oacc[qh][dt][3] * e1 + mOr[d0 + 3] * e2) * inv;
        dst[dt * 8 + lhi * 2] = pk2(v0, v1);
        dst[dt * 8 + lhi * 2 + 1] = pk2(v2, v3);
      }
    }
  }
}

// ---------------------------------------------------------------------------
// Kernel 4: OUT[b,c,n] = sum_d WO[c,d]*O[b,n,d] + BO[c] + x[b,c,n]
// ---------------------------------------------------------------------------
__global__ __launch_bounds__(256) void out_kernel(
    const unsigned short* __restrict__ Ob, const unsigned short* __restrict__ WO,
    const float* __restrict__ BO, const float* __restrict__ x,
    float* __restrict__ out)
{
  int nt = blockIdx.x;
  int ct = blockIdx.y;
  int b = blockIdx.z;
  int w = threadIdx.x >> 6, lane = threadIdx.x & 63;
  int lhi = lane >> 4, llo = lane & 15;
  int cb = ct * 64 + w * 16;

  f32x4 acc[4] = {};
#pragma unroll
  for (int kc = 0; kc < 4; ++kc) {
    bf16x8 af = *(const bf16x8*)(WO + (size_t)(cb + llo) * 128 + kc * 32 + lhi * 8);
#pragma unroll
    for (int nn = 0; nn < 4; ++nn) {
      bf16x8 bfr = *(const bf16x8*)(Ob + ((size_t)b * NN + nt * 64 + nn * 16 + llo) * 128 + kc * 32 + lhi * 8);
      acc[nn] = MFMA16(af, bfr, acc[nn]);
    }
  }
#pragma unroll
  for (int nn = 0; nn < 4; ++nn)
#pragma unroll
    for (int r = 0; r < 4; ++r) {
      int c = cb + lhi * 4 + r;
      int n = nt * 64 + nn * 16 + llo;
      size_t idx = ((size_t)b * CC + c) * NN + n;
      out[idx] = acc[nn][r] + BO[c] + x[idx];
    }
}

// ---------------------------------------------------------------------------
extern "C" void kernel_launch(void* const* d_in, const int* in_sizes, int n_in,
                              void* d_out, int out_size, void* d_ws, size_t ws_size,
                              hipStream_t stream) {
  const float* x = (const float*)d_in[0];
  const float* x1 = (const float*)d_in[1];
  const float* x2 = (const float*)d_in[2];
  const float* bn1_g = (const float*)d_in[3];
  const float* bn1_b = (const float*)d_in[4];
  const float* bn1_m = (const float*)d_in[5];
  const float* bn1_v = (const float*)d_in[6];
  const float* bn2_g = (const float*)d_in[7];
  const float* bn2_b = (const float*)d_in[8];
  const float* bn2_m = (const float*)d_in[9];
  const float* bn2_v = (const float*)d_in[10];
  const float* kq1_w = (const float*)d_in[11];
  const float* kq1_b = (const float*)d_in[12];
  const float* kq2_w = (const float*)d_in[13];
  const float* kq2_b = (const float*)d_in[14];
  const float* v_w = (const float*)d_in[15];
  const float* v_b = (const float*)d_in[16];
  const float* out_w = (const float*)d_in[17];
  const float* out_b = (const float*)d_in[18];
  const float* bnl_g = (const float*)d_in[19];
  const float* bnl_b = (const float*)d_in[20];
  const float* bnl_m = (const float*)d_in[21];
  const float* bnl_v = (const float*)d_in[22];
  const float* w_scale = (const float*)d_in[23];

  char* ws = (char*)d_ws;
  const size_t QKV_SZ = (size_t)NB * 2 * NN * DD * 2;   // 4 MB each
  size_t off = 0;
  unsigned short* Qb = (unsigned short*)(ws + off); off += QKV_SZ;
  unsigned short* Kb = (unsigned short*)(ws + off); off += QKV_SZ;
  unsigned short* Vt = (unsigned short*)(ws + off); off += QKV_SZ;
  unsigned short* Ob = (unsigned short*)(ws + off); off += (size_t)NB * NN * 128 * 2;
  unsigned short* W1 = (unsigned short*)(ws + off); off += 128 * CC * 2;
  unsigned short* W2 = (unsigned short*)(ws + off); off += 128 * CC * 2;
  unsigned short* WV = (unsigned short*)(ws + off); off += 128 * CC * 2;
  unsigned short* WO = (unsigned short*)(ws + off); off += CC * 128 * 2;
  float* B1 = (float*)(ws + off); off += 512;
  float* B2 = (float*)(ws + off); off += 512;
  float* BV = (float*)(ws + off); off += 512;
  float* BO = (float*)(ws + off); off += 1024;
  if (ws_size < off) return;  // loud failure: output stays poisoned

  prep_kernel<<<16, 256, 0, stream>>>(
      kq1_w, kq1_b, kq2_w, kq2_b, v_w, v_b, out_w, out_b,
      bn1_g, bn1_b, bn1_m, bn1_v, bn2_g, bn2_b, bn2_m, bn2_v,
      bnl_g, bnl_b, bnl_m, bnl_v, w_scale,
      W1, W2, WV, WO, B1, B2, BV, BO);

  proj_kernel<<<dim3(64, 3, 4), 256, 0, stream>>>(
      x, x1, x2, W1, W2, WV, B1, B2, BV, Qb, Kb, Vt);

  attn_kernel<<<dim3(64, 2, 4), 256, 0, stream>>>(Qb, Kb, Vt, Ob);

  out_kernel<<<dim3(64, 4, 4), 256, 0, stream>>>(Ob, WO, BO, x, (float*)d_out);
}

// Round 15
// 101.112 us; speedup vs baseline: 1.7803x; 1.0584x over previous
//
#include <hip/hip_runtime.h>

typedef short bf16x8 __attribute__((ext_vector_type(8)));
typedef float f32x4 __attribute__((ext_vector_type(4)));
typedef float f32x2 __attribute__((ext_vector_type(2)));
typedef unsigned short u16x4 __attribute__((ext_vector_type(4)));
typedef unsigned short u16x2 __attribute__((ext_vector_type(2)));

#define MFMA16(A, B, C) __builtin_amdgcn_mfma_f32_16x16x32_bf16((A), (B), (C), 0, 0, 0)

static constexpr int NB = 4;       // batch
static constexpr int CC = 256;     // channels (INC1 == INC2)
static constexpr int NN = 4096;    // H*W
static constexpr int DD = 64;      // head dim

__device__ __forceinline__ unsigned short f2bf(float f) {
  unsigned int u = __builtin_bit_cast(unsigned int, f);
  u += 0x7fffu + ((u >> 16) & 1u);
  return (unsigned short)(u >> 16);
}

__device__ __forceinline__ unsigned int pk2(float lo, float hi) {
  return (unsigned int)f2bf(lo) | ((unsigned int)f2bf(hi) << 16);
}

// T12 recipe: packed f32->bf16x2 convert (RNE), 1 instruction.
__device__ __forceinline__ unsigned int cvtpk(float lo, float hi) {
  unsigned int r;
  asm("v_cvt_pk_bf16_f32 %0, %1, %2" : "=v"(r) : "v"(lo), "v"(hi));
  return r;
}

// LDS 16B-slot swizzle (R5-verified)
__device__ __forceinline__ int swz16(int row) {
  return ((row & 3) | ((((row >> 2) ^ (row >> 3)) & 1) << 2)) << 4;
}

// ---------------------------------------------------------------------------
// Kernel 1: fold BN into projection weights. Grid 16 (R11-verified).
// ---------------------------------------------------------------------------
__global__ __launch_bounds__(256) void prep_kernel(
    const float* __restrict__ kq1_w, const float* __restrict__ kq1_b,
    const float* __restrict__ kq2_w, const float* __restrict__ kq2_b,
    const float* __restrict__ v_w,   const float* __restrict__ v_b,
    const float* __restrict__ out_w, const float* __restrict__ out_b,
    const float* __restrict__ bn1_g, const float* __restrict__ bn1_b,
    const float* __restrict__ bn1_m, const float* __restrict__ bn1_v,
    const float* __restrict__ bn2_g, const float* __restrict__ bn2_b,
    const float* __restrict__ bn2_m, const float* __restrict__ bn2_v,
    const float* __restrict__ bnl_g, const float* __restrict__ bnl_b,
    const float* __restrict__ bnl_m, const float* __restrict__ bnl_v,
    const float* __restrict__ w_scale,
    unsigned short* __restrict__ W1, unsigned short* __restrict__ W2,
    unsigned short* __restrict__ WV, unsigned short* __restrict__ WO,
    float* __restrict__ B1, float* __restrict__ B2,
    float* __restrict__ BV, float* __restrict__ BO)
{
  int blk = blockIdx.x;
  int tid = threadIdx.x;
  int w = tid >> 6, lane = tid & 63;
  if (blk < 12) {
    int mat = blk >> 2, rg = blk & 3;
    const float* Wsrc = mat == 0 ? kq1_w : (mat == 1 ? kq2_w : v_w);
    const float* bsrc = mat == 0 ? kq1_b : (mat == 1 ? kq2_b : v_b);
    unsigned short* Wdst = mat == 0 ? W1 : (mat == 1 ? W2 : WV);
    float* Bdst = mat == 0 ? B1 : (mat == 1 ? B2 : BV);
    __shared__ float s_lds[256], o_lds[256];
    if (mat == 0) {
      float s = bn1_g[tid] * rsqrtf(bn1_v[tid] + 1e-5f);
      s_lds[tid] = s;
      o_lds[tid] = bn1_b[tid] - bn1_m[tid] * s;
    } else if (mat == 1) {
      float s = bn2_g[tid] * rsqrtf(bn2_v[tid] + 1e-5f);
      s_lds[tid] = s;
      o_lds[tid] = bn2_b[tid] - bn2_m[tid] * s;
    } else {
      s_lds[tid] = 1.f;
      o_lds[tid] = 0.f;
    }
    __syncthreads();
    int c = lane * 4;
    for (int row = rg * 32 + w; row < rg * 32 + 32; row += 4) {
      f32x4 wv = *(const f32x4*)(Wsrc + row * CC + c);
      u16x4 o;
      float bacc = 0.f;
#pragma unroll
      for (int j = 0; j < 4; ++j) {
        o[j] = f2bf(wv[j] * s_lds[c + j]);
        bacc += wv[j] * o_lds[c + j];
      }
      *(u16x4*)(Wdst + row * CC + c) = o;
#pragma unroll
      for (int off = 1; off < 64; off <<= 1) bacc += __shfl_xor(bacc, off);
      if (lane == 0) Bdst[row] = bsrc[row] + bacc;
    }
  } else {
    int rg = blk - 12;
    float ws = w_scale[0];
    if (rg == 0) {
      float s = bnl_g[tid] * rsqrtf(bnl_v[tid] + 1e-5f);
      BO[tid] = ws * (out_b[tid] * s + bnl_b[tid] - bnl_m[tid] * s);
    }
    int d = lane * 2;
    for (int row = rg * 64 + w; row < rg * 64 + 64; row += 4) {
      float s = ws * bnl_g[row] * rsqrtf(bnl_v[row] + 1e-5f);
      f32x2 wv = *(const f32x2*)(out_w + row * 128 + d);
      u16x2 o;
      o[0] = f2bf(s * wv[0]);
      o[1] = f2bf(s * wv[1]);
      *(u16x2*)(WO + row * 128 + d) = o;
    }
  }
}

// ---------------------------------------------------------------------------
// Kernel 2: FUSED transpose + projection (R14-verified) + packed Q/K stores.
// ---------------------------------------------------------------------------
__global__ __launch_bounds__(256) void proj_kernel(
    const float* __restrict__ x, const float* __restrict__ x1,
    const float* __restrict__ x2,
    const unsigned short* __restrict__ W1, const unsigned short* __restrict__ W2,
    const unsigned short* __restrict__ WV,
    const float* __restrict__ B1, const float* __restrict__ B2, const float* __restrict__ BV,
    unsigned short* __restrict__ Qb, unsigned short* __restrict__ Kb,
    unsigned short* __restrict__ Vt)
{
  int nt = blockIdx.x;
  int mat = blockIdx.y;
  int b = blockIdx.z;
  const float* src = mat == 0 ? x1 : (mat == 1 ? x2 : x);
  const unsigned short* W = mat == 0 ? W1 : (mat == 1 ? W2 : WV);
  const float* Bi = mat == 0 ? B1 : (mat == 1 ? B2 : BV);
  int t = threadIdx.x;
  int w = t >> 6, lane = t & 63;
  int lhi = lane >> 4, llo = lane & 15;

  __shared__ float ftile[64][65];                 // f32 transpose staging
  __shared__ unsigned short xt[64 * 256];         // bf16 (n,c) tile, swizzled

  // ---- stage: 4 c-subtiles of 64c x 64n ----
  int cl = t >> 2, n0q = (t & 3) * 16;            // global-read mapping
  int nl = t >> 2, c0 = (t & 3) * 16;             // pack mapping
#pragma unroll
  for (int cb = 0; cb < 4; ++cb) {
    const float* s = src + ((size_t)b * CC + cb * 64 + cl) * NN + nt * 64 + n0q;
    f32x4 v0 = *(const f32x4*)(s);
    f32x4 v1 = *(const f32x4*)(s + 4);
    f32x4 v2 = *(const f32x4*)(s + 8);
    f32x4 v3 = *(const f32x4*)(s + 12);
    if (cb) __syncthreads();                      // prev pack done
#pragma unroll
    for (int j = 0; j < 4; ++j) {
      ftile[cl][n0q + j] = v0[j];
      ftile[cl][n0q + 4 + j] = v1[j];
      ftile[cl][n0q + 8 + j] = v2[j];
      ftile[cl][n0q + 12 + j] = v3[j];
    }
    __syncthreads();
    alignas(16) unsigned short tmp[16];
#pragma unroll
    for (int j = 0; j < 16; ++j) tmp[j] = f2bf(ftile[c0 + j][nl]);
    int rowswz = (nl & 7) << 4;
    char* base = (char*)xt + nl * 512;
    *(bf16x8*)(base + ((cb * 128 + c0 * 2) ^ rowswz)) = *(const bf16x8*)(tmp);
    *(bf16x8*)(base + ((cb * 128 + c0 * 2 + 16) ^ rowswz)) = *(const bf16x8*)(tmp + 8);
  }
  __syncthreads();

  // ---- MFMA: C(128 x 64n) = Weff(128x256) @ xt(n,256)^T ----
  int ob = w * 32;
  f32x4 acc[2][4] = {};
#pragma unroll
  for (int kc = 0; kc < 8; ++kc) {
    bf16x8 af[2], bfr[4];
#pragma unroll
    for (int ot = 0; ot < 2; ++ot)
      af[ot] = *(const bf16x8*)(W + (size_t)(ob + ot * 16 + llo) * CC + kc * 32 + lhi * 8);
#pragma unroll
    for (int nn = 0; nn < 4; ++nn) {
      int n = nn * 16 + llo;
      bfr[nn] = *(const bf16x8*)((char*)xt + n * 512 + ((kc * 64 + lhi * 16) ^ ((n & 7) << 4)));
    }
#pragma unroll
    for (int ot = 0; ot < 2; ++ot)
#pragma unroll
      for (int nn = 0; nn < 4; ++nn)
        acc[ot][nn] = MFMA16(af[ot], bfr[nn], acc[ot][nn]);
  }

#pragma unroll
  for (int ot = 0; ot < 2; ++ot)
#pragma unroll
    for (int nn = 0; nn < 4; ++nn) {
      int o0 = ob + ot * 16 + lhi * 4;
      int n = nt * 64 + nn * 16 + llo;
      float v0 = acc[ot][nn][0] + Bi[o0 + 0];
      float v1 = acc[ot][nn][1] + Bi[o0 + 1];
      float v2 = acc[ot][nn][2] + Bi[o0 + 2];
      float v3 = acc[ot][nn][3] + Bi[o0 + 3];
      if (mat < 2) {
        int blk = o0 >> 5;               // const over r: 0:K a0 1:Q a0 2:K a1 3:Q a1
        int aa = blk >> 1;
        int d0 = (o0 & 31) + mat * 32;
        if (blk & 1) {
          v0 *= 0.18033688011f; v1 *= 0.18033688011f;   // 0.125 * log2(e)
          v2 *= 0.18033688011f; v3 *= 0.18033688011f;
        }
        unsigned short* dstp = (blk & 1) ? Qb : Kb;
        unsigned int* p = (unsigned int*)(dstp + ((size_t)(b * 2 + aa) * NN + n) * DD + d0);
        p[0] = pk2(v0, v1);
        p[1] = pk2(v2, v3);
      } else {
        int aa = o0 >> 6;
        int d0 = o0 & 63;
        Vt[((size_t)(b * 2 + aa) * DD + d0 + 0) * NN + n] = f2bf(v0);
        Vt[((size_t)(b * 2 + aa) * DD + d0 + 1) * NN + n] = f2bf(v1);
        Vt[((size_t)(b * 2 + aa) * DD + d0 + 2) * NN + n] = f2bf(v2);
        Vt[((size_t)(b * 2 + aa) * DD + d0 + 3) * NN + n] = f2bf(v3);
      }
    }
}

// ---------------------------------------------------------------------------
// Kernel 3: flash attention — R11-verified best, with XCD-aware 1D grid:
// block i -> head ba = i & 7 (XCDs are assigned round-robin by linear block
// id, so each XCD hosts exactly one head; its 1.5MB Q/K/V set is L2-resident).
// ---------------------------------------------------------------------------
__global__ __launch_bounds__(256, 2) void attn_kernel(
    const unsigned short* __restrict__ Qb, const unsigned short* __restrict__ Kb,
    const unsigned short* __restrict__ Vt, unsigned short* __restrict__ Ob)
{
  int i = blockIdx.x;
  int ba = i & 7;                       // head -> XCD pin
  int qt = i >> 3;                      // 64-q tile
  int a = ba & 1;
  int b = ba >> 1;
  int tid = threadIdx.x;
  int w = tid >> 6;
  int lane = tid & 63;
  int lhi = lane >> 4, llo = lane & 15;
  int wq = w & 1, wk = w >> 1;

  __shared__ char lds[65536];           // [wk][buf][ K 8KB | V 8KB ]

  const unsigned short* Qg = Qb + ((size_t)ba * NN + qt * 64 + wq * 32) * DD;
  bf16x8 qf[2][2];
#pragma unroll
  for (int qh = 0; qh < 2; ++qh)
#pragma unroll
    for (int h = 0; h < 2; ++h)
      qf[qh][h] = *(const bf16x8*)(Qg + (size_t)(qh * 16 + llo) * DD + h * 32 + lhi * 8);

  const unsigned short* Kg = Kb + ((size_t)ba * NN + wk * 2048) * DD;
  const unsigned short* Vg = Vt + (size_t)ba * DD * NN + wk * 2048;

  f32x4 oacc[2][4] = {};
  float m[2] = {-1e30f, -1e30f}, lsum[2] = {0.f, 0.f};

  int t7 = tid & 127;
  int sr8 = t7 >> 3, scol = t7 & 7;

  f32x4 kreg[4], vreg[4];
#define STAGE_LOAD(IT)                                                        \
  {                                                                           \
    int kb_ = (IT) * 64;                                                      \
    _Pragma("unroll") for (int i_ = 0; i_ < 4; ++i_) {                        \
      int row = i_ * 16 + sr8;                                                \
      kreg[i_] = *(const f32x4*)(Kg + (size_t)(kb_ + row) * DD + scol * 8);   \
      vreg[i_] = *(const f32x4*)(Vg + (size_t)row * NN + kb_ + scol * 8);     \
    }                                                                         \
  }
#define STAGE_WRITE(BUF)                                                      \
  {                                                                           \
    char* base_ = lds + wk * 32768 + (BUF) * 16384;                           \
    _Pragma("unroll") for (int i_ = 0; i_ < 4; ++i_) {                        \
      int row = i_ * 16 + sr8;                                                \
      int swz = (scol * 16) ^ swz16(row);                                     \
      *(f32x4*)(base_ + row * 128 + swz) = kreg[i_];                          \
      *(f32x4*)(base_ + 8192 + row * 128 + swz) = vreg[i_];                   \
    }                                                                         \
  }

  STAGE_LOAD(0);
  STAGE_WRITE(0);
  __syncthreads();

  int cur = 0;
  for (int it = 0; it < 32; ++it) {
    if (it < 31) STAGE_LOAD(it + 1);
    const char* Ks = lds + wk * 32768 + cur * 16384;
    const char* Vs = Ks + 8192;

    // S^T = K_perm @ Q (K fragment shared by both qh)
    f32x4 s[2][4] = {};
    __builtin_amdgcn_s_setprio(1);
#pragma unroll
    for (int t = 0; t < 4; ++t) {
      int krow = (t & 1) * 32 + ((llo >> 2) << 3) + ((t >> 1) << 2) + (llo & 3);
      int ksz = swz16(krow);
      const char* kp = Ks + krow * 128;
      bf16x8 k0 = *(const bf16x8*)(kp + ((lhi * 16) ^ ksz));
      bf16x8 k1 = *(const bf16x8*)(kp + ((64 + lhi * 16) ^ ksz));
      s[0][t] = MFMA16(k0, qf[0][0], s[0][t]);
      s[0][t] = MFMA16(k1, qf[0][1], s[0][t]);
      s[1][t] = MFMA16(k0, qf[1][0], s[1][t]);
      s[1][t] = MFMA16(k1, qf[1][1], s[1][t]);
    }
    __builtin_amdgcn_s_setprio(0);

    // online softmax per qh (exp2 domain; lane owns one q per qh)
    union { unsigned int u[4]; bf16x8 v; } F0[2], F1[2];
#pragma unroll
    for (int qh = 0; qh < 2; ++qh) {
      float t0 = fmaxf(fmaxf(s[qh][0][0], s[qh][0][1]), fmaxf(s[qh][0][2], s[qh][0][3]));
      float t1 = fmaxf(fmaxf(s[qh][1][0], s[qh][1][1]), fmaxf(s[qh][1][2], s[qh][1][3]));
      float t2 = fmaxf(fmaxf(s[qh][2][0], s[qh][2][1]), fmaxf(s[qh][2][2], s[qh][2][3]));
      float t3 = fmaxf(fmaxf(s[qh][3][0], s[qh][3][1]), fmaxf(s[qh][3][2], s[qh][3][3]));
      float pm = fmaxf(fmaxf(t0, t1), fmaxf(t2, t3));
      pm = fmaxf(pm, __shfl_xor(pm, 16));
      pm = fmaxf(pm, __shfl_xor(pm, 32));
      if (__any(pm > m[qh])) {   // exact skip: pm<=m everywhere => al==1
        float mn = fmaxf(m[qh], pm);
        float al = __builtin_amdgcn_exp2f(m[qh] - mn);
        m[qh] = mn;
        lsum[qh] *= al;
#pragma unroll
        for (int dt = 0; dt < 4; ++dt)
#pragma unroll
          for (int r = 0; r < 4; ++r) oacc[qh][dt][r] *= al;
      }
#pragma unroll
      for (int t = 0; t < 4; ++t)
#pragma unroll
        for (int r = 0; r < 4; ++r)
          s[qh][t][r] = __builtin_amdgcn_exp2f(s[qh][t][r] - m[qh]);
      float p0 = (s[qh][0][0] + s[qh][0][1]) + (s[qh][0][2] + s[qh][0][3]);
      float p1 = (s[qh][1][0] + s[qh][1][1]) + (s[qh][1][2] + s[qh][1][3]);
      float p2 = (s[qh][2][0] + s[qh][2][1]) + (s[qh][2][2] + s[qh][2][3]);
      float p3 = (s[qh][3][0] + s[qh][3][1]) + (s[qh][3][2] + s[qh][3][3]);
      lsum[qh] += (p0 + p1) + (p2 + p3);

      F0[qh].u[0] = cvtpk(s[qh][0][0], s[qh][0][1]); F0[qh].u[1] = cvtpk(s[qh][0][2], s[qh][0][3]);
      F0[qh].u[2] = cvtpk(s[qh][2][0], s[qh][2][1]); F0[qh].u[3] = cvtpk(s[qh][2][2], s[qh][2][3]);
      F1[qh].u[0] = cvtpk(s[qh][1][0], s[qh][1][1]); F1[qh].u[1] = cvtpk(s[qh][1][2], s[qh][1][3]);
      F1[qh].u[2] = cvtpk(s[qh][3][0], s[qh][3][1]); F1[qh].u[3] = cvtpk(s[qh][3][2], s[qh][3][3]);
    }

    // O^T += V^T @ P^T (V fragment shared by both qh)
    __builtin_amdgcn_s_setprio(1);
#pragma unroll
    for (int dt = 0; dt < 4; ++dt) {
      int vrow = dt * 16 + llo;
      int vsz = swz16(vrow);
      const char* vp = Vs + vrow * 128;
      bf16x8 v0 = *(const bf16x8*)(vp + ((lhi * 16) ^ vsz));
      bf16x8 v1 = *(const bf16x8*)(vp + ((64 + lhi * 16) ^ vsz));
      oacc[0][dt] = MFMA16(v0, F0[0].v, oacc[0][dt]);
      oacc[0][dt] = MFMA16(v1, F1[0].v, oacc[0][dt]);
      oacc[1][dt] = MFMA16(v0, F0[1].v, oacc[1][dt]);
      oacc[1][dt] = MFMA16(v1, F1[1].v, oacc[1][dt]);
    }
    __builtin_amdgcn_s_setprio(0);

    if (it < 31) STAGE_WRITE(cur ^ 1);  // other buffer: no pre-write drain
    __syncthreads();                    // publish writes + fence next iter
    cur ^= 1;
  }

#pragma unroll
  for (int qh = 0; qh < 2; ++qh) {
    lsum[qh] += __shfl_xor(lsum[qh], 16);
    lsum[qh] += __shfl_xor(lsum[qh], 32);
  }

  // merge the two wk-halves via LDS (stride 65)
  float* mO = (float*)lds;               // [64 q][65]
  float* mM = (float*)lds + 64 * 65;     // [64]
  float* mL = mM + 64;
  if (wk == 1) {
#pragma unroll
    for (int qh = 0; qh < 2; ++qh) {
      int ql = wq * 32 + qh * 16 + llo;
#pragma unroll
      for (int dt = 0; dt < 4; ++dt)
#pragma unroll
        for (int r = 0; r < 4; ++r)
          mO[ql * 65 + dt * 16 + lhi * 4 + r] = oacc[qh][dt][r];
      if (lhi == 0) { mM[ql] = m[qh]; mL[ql] = lsum[qh]; }
    }
  }
  __syncthreads();
  if (wk == 0) {
#pragma unroll
    for (int qh = 0; qh < 2; ++qh) {
      int ql = wq * 32 + qh * 16 + llo;
      float m2 = mM[ql], l2 = mL[ql];
      float mf = fmaxf(m[qh], m2);
      float e1 = __builtin_amdgcn_exp2f(m[qh] - mf);
      float e2 = __builtin_amdgcn_exp2f(m2 - mf);
      float inv = 1.f / (lsum[qh] * e1 + l2 * e2);
      int qglob = qt * 64 + ql;
      unsigned int* dst = (unsigned int*)(Ob + ((size_t)b * NN + qglob) * 128 + a * 64);
      const float* mOr = mO + ql * 65;
#pragma unroll
      for (int dt = 0; dt < 4; ++dt) {
        int d0 = dt * 16 + lhi * 4;
        float v0 = (oacc[qh][dt][0] * e1 + mOr[d0 + 0] * e2) * inv;
        float v1 = (oacc[qh][dt][1] * e1 + mOr[d0 + 1] * e2) * inv;
        float v2 = (oacc[qh][dt][2] * e1 + mOr[d0 + 2] * e2) * inv;
        float v3 = (oacc[qh][dt][3] * e1 + mOr[d0 + 3] * e2) * inv;
        dst[dt * 8 + lhi * 2] = pk2(v0, v1);
        dst[dt * 8 + lhi * 2 + 1] = pk2(v2, v3);
      }
    }
  }
}

// ---------------------------------------------------------------------------
// Kernel 4: OUT[b,c,n] = sum_d WO[c,d]*O[b,n,d] + BO[c] + x[b,c,n]
// ---------------------------------------------------------------------------
__global__ __launch_bounds__(256) void out_kernel(
    const unsigned short* __restrict__ Ob, const unsigned short* __restrict__ WO,
    const float* __restrict__ BO, const float* __restrict__ x,
    float* __restrict__ out)
{
  int nt = blockIdx.x;
  int ct = blockIdx.y;
  int b = blockIdx.z;
  int w = threadIdx.x >> 6, lane = threadIdx.x & 63;
  int lhi = lane >> 4, llo = lane & 15;
  int cb = ct * 64 + w * 16;

  f32x4 acc[4] = {};
#pragma unroll
  for (int kc = 0; kc < 4; ++kc) {
    bf16x8 af = *(const bf16x8*)(WO + (size_t)(cb + llo) * 128 + kc * 32 + lhi * 8);
#pragma unroll
    for (int nn = 0; nn < 4; ++nn) {
      bf16x8 bfr = *(const bf16x8*)(Ob + ((size_t)b * NN + nt * 64 + nn * 16 + llo) * 128 + kc * 32 + lhi * 8);
      acc[nn] = MFMA16(af, bfr, acc[nn]);
    }
  }
#pragma unroll
  for (int nn = 0; nn < 4; ++nn)
#pragma unroll
    for (int r = 0; r < 4; ++r) {
      int c = cb + lhi * 4 + r;
      int n = nt * 64 + nn * 16 + llo;
      size_t idx = ((size_t)b * CC + c) * NN + n;
      out[idx] = acc[nn][r] + BO[c] + x[idx];
    }
}

// ---------------------------------------------------------------------------
extern "C" void kernel_launch(void* const* d_in, const int* in_sizes, int n_in,
                              void* d_out, int out_size, void* d_ws, size_t ws_size,
                              hipStream_t stream) {
  const float* x = (const float*)d_in[0];
  const float* x1 = (const float*)d_in[1];
  const float* x2 = (const float*)d_in[2];
  const float* bn1_g = (const float*)d_in[3];
  const float* bn1_b = (const float*)d_in[4];
  const float* bn1_m = (const float*)d_in[5];
  const float* bn1_v = (const float*)d_in[6];
  const float* bn2_g = (const float*)d_in[7];
  const float* bn2_b = (const float*)d_in[8];
  const float* bn2_m = (const float*)d_in[9];
  const float* bn2_v = (const float*)d_in[10];
  const float* kq1_w = (const float*)d_in[11];
  const float* kq1_b = (const float*)d_in[12];
  const float* kq2_w = (const float*)d_in[13];
  const float* kq2_b = (const float*)d_in[14];
  const float* v_w = (const float*)d_in[15];
  const float* v_b = (const float*)d_in[16];
  const float* out_w = (const float*)d_in[17];
  const float* out_b = (const float*)d_in[18];
  const float* bnl_g = (const float*)d_in[19];
  const float* bnl_b = (const float*)d_in[20];
  const float* bnl_m = (const float*)d_in[21];
  const float* bnl_v = (const float*)d_in[22];
  const float* w_scale = (const float*)d_in[23];

  char* ws = (char*)d_ws;
  const size_t QKV_SZ = (size_t)NB * 2 * NN * DD * 2;   // 4 MB each
  size_t off = 0;
  unsigned short* Qb = (unsigned short*)(ws + off); off += QKV_SZ;
  unsigned short* Kb = (unsigned short*)(ws + off); off += QKV_SZ;
  unsigned short* Vt = (unsigned short*)(ws + off); off += QKV_SZ;
  unsigned short* Ob = (unsigned short*)(ws + off); off += (size_t)NB * NN * 128 * 2;
  unsigned short* W1 = (unsigned short*)(ws + off); off += 128 * CC * 2;
  unsigned short* W2 = (unsigned short*)(ws + off); off += 128 * CC * 2;
  unsigned short* WV = (unsigned short*)(ws + off); off += 128 * CC * 2;
  unsigned short* WO = (unsigned short*)(ws + off); off += CC * 128 * 2;
  float* B1 = (float*)(ws + off); off += 512;
  float* B2 = (float*)(ws + off); off += 512;
  float* BV = (float*)(ws + off); off += 512;
  float* BO = (float*)(ws + off); off += 1024;
  if (ws_size < off) return;  // loud failure: output stays poisoned

  prep_kernel<<<16, 256, 0, stream>>>(
      kq1_w, kq1_b, kq2_w, kq2_b, v_w, v_b, out_w, out_b,
      bn1_g, bn1_b, bn1_m, bn1_v, bn2_g, bn2_b, bn2_m, bn2_v,
      bnl_g, bnl_b, bnl_m, bnl_v, w_scale,
      W1, W2, WV, WO, B1, B2, BV, BO);

  proj_kernel<<<dim3(64, 3, 4), 256, 0, stream>>>(
      x, x1, x2, W1, W2, WV, B1, B2, BV, Qb, Kb, Vt);

  attn_kernel<<<dim3(512, 1, 1), 256, 0, stream>>>(Qb, Kb, Vt, Ob);

  out_kernel<<<dim3(64, 4, 4), 256, 0, stream>>>(Ob, WO, BO, x, (float*)d_out);
}

// Round 16
// 99.412 us; speedup vs baseline: 1.8108x; 1.0171x over previous
//
#include <hip/hip_runtime.h>

typedef short bf16x8 __attribute__((ext_vector_type(8)));
typedef float f32x4 __attribute__((ext_vector_type(4)));
typedef float f32x2 __attribute__((ext_vector_type(2)));
typedef unsigned short u16x4 __attribute__((ext_vector_type(4)));
typedef unsigned short u16x2 __attribute__((ext_vector_type(2)));

#define MFMA16(A, B, C) __builtin_amdgcn_mfma_f32_16x16x32_bf16((A), (B), (C), 0, 0, 0)

static constexpr int NB = 4;       // batch
static constexpr int CC = 256;     // channels (INC1 == INC2)
static constexpr int NN = 4096;    // H*W
static constexpr int DD = 64;      // head dim

__device__ __forceinline__ unsigned short f2bf(float f) {
  unsigned int u = __builtin_bit_cast(unsigned int, f);
  u += 0x7fffu + ((u >> 16) & 1u);
  return (unsigned short)(u >> 16);
}

__device__ __forceinline__ unsigned int pk2(float lo, float hi) {
  return (unsigned int)f2bf(lo) | ((unsigned int)f2bf(hi) << 16);
}

// T12 recipe: packed f32->bf16x2 convert (RNE), 1 instruction.
__device__ __forceinline__ unsigned int cvtpk(float lo, float hi) {
  unsigned int r;
  asm("v_cvt_pk_bf16_f32 %0, %1, %2" : "=v"(r) : "v"(lo), "v"(hi));
  return r;
}

// 3-input max: clang fuses nested fmaxf into v_max3_f32 (T17).
__device__ __forceinline__ float max3f(float a, float b, float c) {
  return fmaxf(fmaxf(a, b), c);
}

// LDS 16B-slot swizzle (R5-verified)
__device__ __forceinline__ int swz16(int row) {
  return ((row & 3) | ((((row >> 2) ^ (row >> 3)) & 1) << 2)) << 4;
}

// ---------------------------------------------------------------------------
// Kernel 1: fold BN into projection weights. Grid 16 (R11-verified).
// ---------------------------------------------------------------------------
__global__ __launch_bounds__(256) void prep_kernel(
    const float* __restrict__ kq1_w, const float* __restrict__ kq1_b,
    const float* __restrict__ kq2_w, const float* __restrict__ kq2_b,
    const float* __restrict__ v_w,   const float* __restrict__ v_b,
    const float* __restrict__ out_w, const float* __restrict__ out_b,
    const float* __restrict__ bn1_g, const float* __restrict__ bn1_b,
    const float* __restrict__ bn1_m, const float* __restrict__ bn1_v,
    const float* __restrict__ bn2_g, const float* __restrict__ bn2_b,
    const float* __restrict__ bn2_m, const float* __restrict__ bn2_v,
    const float* __restrict__ bnl_g, const float* __restrict__ bnl_b,
    const float* __restrict__ bnl_m, const float* __restrict__ bnl_v,
    const float* __restrict__ w_scale,
    unsigned short* __restrict__ W1, unsigned short* __restrict__ W2,
    unsigned short* __restrict__ WV, unsigned short* __restrict__ WO,
    float* __restrict__ B1, float* __restrict__ B2,
    float* __restrict__ BV, float* __restrict__ BO)
{
  int blk = blockIdx.x;
  int tid = threadIdx.x;
  int w = tid >> 6, lane = tid & 63;
  if (blk < 12) {
    int mat = blk >> 2, rg = blk & 3;
    const float* Wsrc = mat == 0 ? kq1_w : (mat == 1 ? kq2_w : v_w);
    const float* bsrc = mat == 0 ? kq1_b : (mat == 1 ? kq2_b : v_b);
    unsigned short* Wdst = mat == 0 ? W1 : (mat == 1 ? W2 : WV);
    float* Bdst = mat == 0 ? B1 : (mat == 1 ? B2 : BV);
    __shared__ float s_lds[256], o_lds[256];
    if (mat == 0) {
      float s = bn1_g[tid] * rsqrtf(bn1_v[tid] + 1e-5f);
      s_lds[tid] = s;
      o_lds[tid] = bn1_b[tid] - bn1_m[tid] * s;
    } else if (mat == 1) {
      float s = bn2_g[tid] * rsqrtf(bn2_v[tid] + 1e-5f);
      s_lds[tid] = s;
      o_lds[tid] = bn2_b[tid] - bn2_m[tid] * s;
    } else {
      s_lds[tid] = 1.f;
      o_lds[tid] = 0.f;
    }
    __syncthreads();
    int c = lane * 4;
    for (int row = rg * 32 + w; row < rg * 32 + 32; row += 4) {
      f32x4 wv = *(const f32x4*)(Wsrc + row * CC + c);
      u16x4 o;
      float bacc = 0.f;
#pragma unroll
      for (int j = 0; j < 4; ++j) {
        o[j] = f2bf(wv[j] * s_lds[c + j]);
        bacc += wv[j] * o_lds[c + j];
      }
      *(u16x4*)(Wdst + row * CC + c) = o;
#pragma unroll
      for (int off = 1; off < 64; off <<= 1) bacc += __shfl_xor(bacc, off);
      if (lane == 0) Bdst[row] = bsrc[row] + bacc;
    }
  } else {
    int rg = blk - 12;
    float ws = w_scale[0];
    if (rg == 0) {
      float s = bnl_g[tid] * rsqrtf(bnl_v[tid] + 1e-5f);
      BO[tid] = ws * (out_b[tid] * s + bnl_b[tid] - bnl_m[tid] * s);
    }
    int d = lane * 2;
    for (int row = rg * 64 + w; row < rg * 64 + 64; row += 4) {
      float s = ws * bnl_g[row] * rsqrtf(bnl_v[row] + 1e-5f);
      f32x2 wv = *(const f32x2*)(out_w + row * 128 + d);
      u16x2 o;
      o[0] = f2bf(s * wv[0]);
      o[1] = f2bf(s * wv[1]);
      *(u16x2*)(WO + row * 128 + d) = o;
    }
  }
}

// ---------------------------------------------------------------------------
// Kernel 2: FUSED transpose + projection (R14/R15-verified).
// ---------------------------------------------------------------------------
__global__ __launch_bounds__(256) void proj_kernel(
    const float* __restrict__ x, const float* __restrict__ x1,
    const float* __restrict__ x2,
    const unsigned short* __restrict__ W1, const unsigned short* __restrict__ W2,
    const unsigned short* __restrict__ WV,
    const float* __restrict__ B1, const float* __restrict__ B2, const float* __restrict__ BV,
    unsigned short* __restrict__ Qb, unsigned short* __restrict__ Kb,
    unsigned short* __restrict__ Vt)
{
  int nt = blockIdx.x;
  int mat = blockIdx.y;
  int b = blockIdx.z;
  const float* src = mat == 0 ? x1 : (mat == 1 ? x2 : x);
  const unsigned short* W = mat == 0 ? W1 : (mat == 1 ? W2 : WV);
  const float* Bi = mat == 0 ? B1 : (mat == 1 ? B2 : BV);
  int t = threadIdx.x;
  int w = t >> 6, lane = t & 63;
  int lhi = lane >> 4, llo = lane & 15;

  __shared__ float ftile[64][65];                 // f32 transpose staging
  __shared__ unsigned short xt[64 * 256];         // bf16 (n,c) tile, swizzled

  // ---- stage: 4 c-subtiles of 64c x 64n ----
  int cl = t >> 2, n0q = (t & 3) * 16;            // global-read mapping
  int nl = t >> 2, c0 = (t & 3) * 16;             // pack mapping
#pragma unroll
  for (int cb = 0; cb < 4; ++cb) {
    const float* s = src + ((size_t)b * CC + cb * 64 + cl) * NN + nt * 64 + n0q;
    f32x4 v0 = *(const f32x4*)(s);
    f32x4 v1 = *(const f32x4*)(s + 4);
    f32x4 v2 = *(const f32x4*)(s + 8);
    f32x4 v3 = *(const f32x4*)(s + 12);
    if (cb) __syncthreads();                      // prev pack done
#pragma unroll
    for (int j = 0; j < 4; ++j) {
      ftile[cl][n0q + j] = v0[j];
      ftile[cl][n0q + 4 + j] = v1[j];
      ftile[cl][n0q + 8 + j] = v2[j];
      ftile[cl][n0q + 12 + j] = v3[j];
    }
    __syncthreads();
    alignas(16) unsigned short tmp[16];
#pragma unroll
    for (int j = 0; j < 16; ++j) tmp[j] = f2bf(ftile[c0 + j][nl]);
    int rowswz = (nl & 7) << 4;
    char* base = (char*)xt + nl * 512;
    *(bf16x8*)(base + ((cb * 128 + c0 * 2) ^ rowswz)) = *(const bf16x8*)(tmp);
    *(bf16x8*)(base + ((cb * 128 + c0 * 2 + 16) ^ rowswz)) = *(const bf16x8*)(tmp + 8);
  }
  __syncthreads();

  // ---- MFMA: C(128 x 64n) = Weff(128x256) @ xt(n,256)^T ----
  int ob = w * 32;
  f32x4 acc[2][4] = {};
#pragma unroll
  for (int kc = 0; kc < 8; ++kc) {
    bf16x8 af[2], bfr[4];
#pragma unroll
    for (int ot = 0; ot < 2; ++ot)
      af[ot] = *(const bf16x8*)(W + (size_t)(ob + ot * 16 + llo) * CC + kc * 32 + lhi * 8);
#pragma unroll
    for (int nn = 0; nn < 4; ++nn) {
      int n = nn * 16 + llo;
      bfr[nn] = *(const bf16x8*)((char*)xt + n * 512 + ((kc * 64 + lhi * 16) ^ ((n & 7) << 4)));
    }
#pragma unroll
    for (int ot = 0; ot < 2; ++ot)
#pragma unroll
      for (int nn = 0; nn < 4; ++nn)
        acc[ot][nn] = MFMA16(af[ot], bfr[nn], acc[ot][nn]);
  }

#pragma unroll
  for (int ot = 0; ot < 2; ++ot)
#pragma unroll
    for (int nn = 0; nn < 4; ++nn) {
      int o0 = ob + ot * 16 + lhi * 4;
      int n = nt * 64 + nn * 16 + llo;
      float v0 = acc[ot][nn][0] + Bi[o0 + 0];
      float v1 = acc[ot][nn][1] + Bi[o0 + 1];
      float v2 = acc[ot][nn][2] + Bi[o0 + 2];
      float v3 = acc[ot][nn][3] + Bi[o0 + 3];
      if (mat < 2) {
        int blk = o0 >> 5;               // const over r: 0:K a0 1:Q a0 2:K a1 3:Q a1
        int aa = blk >> 1;
        int d0 = (o0 & 31) + mat * 32;
        if (blk & 1) {
          v0 *= 0.18033688011f; v1 *= 0.18033688011f;   // 0.125 * log2(e)
          v2 *= 0.18033688011f; v3 *= 0.18033688011f;
        }
        unsigned short* dstp = (blk & 1) ? Qb : Kb;
        unsigned int* p = (unsigned int*)(dstp + ((size_t)(b * 2 + aa) * NN + n) * DD + d0);
        p[0] = pk2(v0, v1);
        p[1] = pk2(v2, v3);
      } else {
        int aa = o0 >> 6;
        int d0 = o0 & 63;
        Vt[((size_t)(b * 2 + aa) * DD + d0 + 0) * NN + n] = f2bf(v0);
        Vt[((size_t)(b * 2 + aa) * DD + d0 + 1) * NN + n] = f2bf(v1);
        Vt[((size_t)(b * 2 + aa) * DD + d0 + 2) * NN + n] = f2bf(v2);
        Vt[((size_t)(b * 2 + aa) * DD + d0 + 3) * NN + n] = f2bf(v3);
      }
    }
}

// ---------------------------------------------------------------------------
// Kernel 3: flash attention — R15-verified (XCD head pin) + max3 reduce trees
// + STAGE_WRITE hoisted before PV (write drain overlaps PV MFMA latency).
// ---------------------------------------------------------------------------
__global__ __launch_bounds__(256, 2) void attn_kernel(
    const unsigned short* __restrict__ Qb, const unsigned short* __restrict__ Kb,
    const unsigned short* __restrict__ Vt, unsigned short* __restrict__ Ob)
{
  int i = blockIdx.x;
  int ba = i & 7;                       // head -> XCD pin (R15-verified)
  int qt = i >> 3;                      // 64-q tile
  int a = ba & 1;
  int b = ba >> 1;
  int tid = threadIdx.x;
  int w = tid >> 6;
  int lane = tid & 63;
  int lhi = lane >> 4, llo = lane & 15;
  int wq = w & 1, wk = w >> 1;

  __shared__ char lds[65536];           // [wk][buf][ K 8KB | V 8KB ]

  const unsigned short* Qg = Qb + ((size_t)ba * NN + qt * 64 + wq * 32) * DD;
  bf16x8 qf[2][2];
#pragma unroll
  for (int qh = 0; qh < 2; ++qh)
#pragma unroll
    for (int h = 0; h < 2; ++h)
      qf[qh][h] = *(const bf16x8*)(Qg + (size_t)(qh * 16 + llo) * DD + h * 32 + lhi * 8);

  const unsigned short* Kg = Kb + ((size_t)ba * NN + wk * 2048) * DD;
  const unsigned short* Vg = Vt + (size_t)ba * DD * NN + wk * 2048;

  f32x4 oacc[2][4] = {};
  float m[2] = {-1e30f, -1e30f}, lsum[2] = {0.f, 0.f};

  int t7 = tid & 127;
  int sr8 = t7 >> 3, scol = t7 & 7;

  f32x4 kreg[4], vreg[4];
#define STAGE_LOAD(IT)                                                        \
  {                                                                           \
    int kb_ = (IT) * 64;                                                      \
    _Pragma("unroll") for (int i_ = 0; i_ < 4; ++i_) {                        \
      int row = i_ * 16 + sr8;                                                \
      kreg[i_] = *(const f32x4*)(Kg + (size_t)(kb_ + row) * DD + scol * 8);   \
      vreg[i_] = *(const f32x4*)(Vg + (size_t)row * NN + kb_ + scol * 8);     \
    }                                                                         \
  }
#define STAGE_WRITE(BUF)                                                      \
  {                                                                           \
    char* base_ = lds + wk * 32768 + (BUF) * 16384;                           \
    _Pragma("unroll") for (int i_ = 0; i_ < 4; ++i_) {                        \
      int row = i_ * 16 + sr8;                                                \
      int swz = (scol * 16) ^ swz16(row);                                     \
      *(f32x4*)(base_ + row * 128 + swz) = kreg[i_];                          \
      *(f32x4*)(base_ + 8192 + row * 128 + swz) = vreg[i_];                   \
    }                                                                         \
  }

  STAGE_LOAD(0);
  STAGE_WRITE(0);
  __syncthreads();

  int cur = 0;
  for (int it = 0; it < 32; ++it) {
    if (it < 31) STAGE_LOAD(it + 1);
    const char* Ks = lds + wk * 32768 + cur * 16384;
    const char* Vs = Ks + 8192;

    // S^T = K_perm @ Q (K fragment shared by both qh)
    f32x4 s[2][4] = {};
    __builtin_amdgcn_s_setprio(1);
#pragma unroll
    for (int t = 0; t < 4; ++t) {
      int krow = (t & 1) * 32 + ((llo >> 2) << 3) + ((t >> 1) << 2) + (llo & 3);
      int ksz = swz16(krow);
      const char* kp = Ks + krow * 128;
      bf16x8 k0 = *(const bf16x8*)(kp + ((lhi * 16) ^ ksz));
      bf16x8 k1 = *(const bf16x8*)(kp + ((64 + lhi * 16) ^ ksz));
      s[0][t] = MFMA16(k0, qf[0][0], s[0][t]);
      s[0][t] = MFMA16(k1, qf[0][1], s[0][t]);
      s[1][t] = MFMA16(k0, qf[1][0], s[1][t]);
      s[1][t] = MFMA16(k1, qf[1][1], s[1][t]);
    }
    __builtin_amdgcn_s_setprio(0);

    // online softmax per qh (exp2 domain; lane owns one q per qh)
    union { unsigned int u[4]; bf16x8 v; } F0[2], F1[2];
#pragma unroll
    for (int qh = 0; qh < 2; ++qh) {
      // max3-structured reduce (8 ops, depth 3)
      float g0 = max3f(s[qh][0][0], s[qh][0][1], s[qh][0][2]);
      float g1 = max3f(s[qh][0][3], s[qh][1][0], s[qh][1][1]);
      float g2 = max3f(s[qh][1][2], s[qh][1][3], s[qh][2][0]);
      float g3 = max3f(s[qh][2][1], s[qh][2][2], s[qh][2][3]);
      float g4 = max3f(s[qh][3][0], s[qh][3][1], s[qh][3][2]);
      float h0 = max3f(g0, g1, g2);
      float h1 = max3f(g3, g4, s[qh][3][3]);
      float pm = fmaxf(h0, h1);
      pm = fmaxf(pm, __shfl_xor(pm, 16));
      pm = fmaxf(pm, __shfl_xor(pm, 32));
      if (__any(pm > m[qh])) {   // exact skip: pm<=m everywhere => al==1
        float mn = fmaxf(m[qh], pm);
        float al = __builtin_amdgcn_exp2f(m[qh] - mn);
        m[qh] = mn;
        lsum[qh] *= al;
#pragma unroll
        for (int dt = 0; dt < 4; ++dt)
#pragma unroll
          for (int r = 0; r < 4; ++r) oacc[qh][dt][r] *= al;
      }
#pragma unroll
      for (int t = 0; t < 4; ++t)
#pragma unroll
        for (int r = 0; r < 4; ++r)
          s[qh][t][r] = __builtin_amdgcn_exp2f(s[qh][t][r] - m[qh]);
      float p0 = (s[qh][0][0] + s[qh][0][1]) + (s[qh][0][2] + s[qh][0][3]);
      float p1 = (s[qh][1][0] + s[qh][1][1]) + (s[qh][1][2] + s[qh][1][3]);
      float p2 = (s[qh][2][0] + s[qh][2][1]) + (s[qh][2][2] + s[qh][2][3]);
      float p3 = (s[qh][3][0] + s[qh][3][1]) + (s[qh][3][2] + s[qh][3][3]);
      lsum[qh] += (p0 + p1) + (p2 + p3);

      F0[qh].u[0] = cvtpk(s[qh][0][0], s[qh][0][1]); F0[qh].u[1] = cvtpk(s[qh][0][2], s[qh][0][3]);
      F0[qh].u[2] = cvtpk(s[qh][2][0], s[qh][2][1]); F0[qh].u[3] = cvtpk(s[qh][2][2], s[qh][2][3]);
      F1[qh].u[0] = cvtpk(s[qh][1][0], s[qh][1][1]); F1[qh].u[1] = cvtpk(s[qh][1][2], s[qh][1][3]);
      F1[qh].u[2] = cvtpk(s[qh][3][0], s[qh][3][1]); F1[qh].u[3] = cvtpk(s[qh][3][2], s[qh][3][3]);
    }

    // hoisted: stage next tile into the other buffer BEFORE PV so the
    // ds_writes drain under the PV MFMA latency (no hazard: disjoint buffer)
    if (it < 31) STAGE_WRITE(cur ^ 1);

    // O^T += V^T @ P^T (V fragment shared by both qh)
    __builtin_amdgcn_s_setprio(1);
#pragma unroll
    for (int dt = 0; dt < 4; ++dt) {
      int vrow = dt * 16 + llo;
      int vsz = swz16(vrow);
      const char* vp = Vs + vrow * 128;
      bf16x8 v0 = *(const bf16x8*)(vp + ((lhi * 16) ^ vsz));
      bf16x8 v1 = *(const bf16x8*)(vp + ((64 + lhi * 16) ^ vsz));
      oacc[0][dt] = MFMA16(v0, F0[0].v, oacc[0][dt]);
      oacc[0][dt] = MFMA16(v1, F1[0].v, oacc[0][dt]);
      oacc[1][dt] = MFMA16(v0, F0[1].v, oacc[1][dt]);
      oacc[1][dt] = MFMA16(v1, F1[1].v, oacc[1][dt]);
    }
    __builtin_amdgcn_s_setprio(0);

    __syncthreads();                    // publish writes + fence next iter
    cur ^= 1;
  }

#pragma unroll
  for (int qh = 0; qh < 2; ++qh) {
    lsum[qh] += __shfl_xor(lsum[qh], 16);
    lsum[qh] += __shfl_xor(lsum[qh], 32);
  }

  // merge the two wk-halves via LDS (stride 65)
  float* mO = (float*)lds;               // [64 q][65]
  float* mM = (float*)lds + 64 * 65;     // [64]
  float* mL = mM + 64;
  if (wk == 1) {
#pragma unroll
    for (int qh = 0; qh < 2; ++qh) {
      int ql = wq * 32 + qh * 16 + llo;
#pragma unroll
      for (int dt = 0; dt < 4; ++dt)
#pragma unroll
        for (int r = 0; r < 4; ++r)
          mO[ql * 65 + dt * 16 + lhi * 4 + r] = oacc[qh][dt][r];
      if (lhi == 0) { mM[ql] = m[qh]; mL[ql] = lsum[qh]; }
    }
  }
  __syncthreads();
  if (wk == 0) {
#pragma unroll
    for (int qh = 0; qh < 2; ++qh) {
      int ql = wq * 32 + qh * 16 + llo;
      float m2 = mM[ql], l2 = mL[ql];
      float mf = fmaxf(m[qh], m2);
      float e1 = __builtin_amdgcn_exp2f(m[qh] - mf);
      float e2 = __builtin_amdgcn_exp2f(m2 - mf);
      float inv = 1.f / (lsum[qh] * e1 + l2 * e2);
      int qglob = qt * 64 + ql;
      unsigned int* dst = (unsigned int*)(Ob + ((size_t)b * NN + qglob) * 128 + a * 64);
      const float* mOr = mO + ql * 65;
#pragma unroll
      for (int dt = 0; dt < 4; ++dt) {
        int d0 = dt * 16 + lhi * 4;
        float v0 = (oacc[qh][dt][0] * e1 + mOr[d0 + 0] * e2) * inv;
        float v1 = (oacc[qh][dt][1] * e1 + mOr[d0 + 1] * e2) * inv;
        float v2 = (oacc[qh][dt][2] * e1 + mOr[d0 + 2] * e2) * inv;
        float v3 = (oacc[qh][dt][3] * e1 + mOr[d0 + 3] * e2) * inv;
        dst[dt * 8 + lhi * 2] = pk2(v0, v1);
        dst[dt * 8 + lhi * 2 + 1] = pk2(v2, v3);
      }
    }
  }
}

// ---------------------------------------------------------------------------
// Kernel 4: OUT[b,c,n] = sum_d WO[c,d]*O[b,n,d] + BO[c] + x[b,c,n]
// 1D XCD-congruent grid: id = ct*256 + nt*4 + b, so the 4 ct-blocks sharing
// one Ob slice have ids congruent mod 8 -> same XCD -> Ob re-reads L2-hit.
// ---------------------------------------------------------------------------
__global__ __launch_bounds__(256) void out_kernel(
    const unsigned short* __restrict__ Ob, const unsigned short* __restrict__ WO,
    const float* __restrict__ BO, const float* __restrict__ x,
    float* __restrict__ out)
{
  int id = blockIdx.x;
  int ct = id >> 8;
  int r8 = id & 255;
  int nt = r8 >> 2;
  int b = r8 & 3;
  int w = threadIdx.x >> 6, lane = threadIdx.x & 63;
  int lhi = lane >> 4, llo = lane & 15;
  int cb = ct * 64 + w * 16;

  f32x4 acc[4] = {};
#pragma unroll
  for (int kc = 0; kc < 4; ++kc) {
    bf16x8 af = *(const bf16x8*)(WO + (size_t)(cb + llo) * 128 + kc * 32 + lhi * 8);
#pragma unroll
    for (int nn = 0; nn < 4; ++nn) {
      bf16x8 bfr = *(const bf16x8*)(Ob + ((size_t)b * NN + nt * 64 + nn * 16 + llo) * 128 + kc * 32 + lhi * 8);
      acc[nn] = MFMA16(af, bfr, acc[nn]);
    }
  }
#pragma unroll
  for (int nn = 0; nn < 4; ++nn)
#pragma unroll
    for (int r = 0; r < 4; ++r) {
      int c = cb + lhi * 4 + r;
      int n = nt * 64 + nn * 16 + llo;
      size_t idx = ((size_t)b * CC + c) * NN + n;
      out[idx] = acc[nn][r] + BO[c] + x[idx];
    }
}

// ---------------------------------------------------------------------------
extern "C" void kernel_launch(void* const* d_in, const int* in_sizes, int n_in,
                              void* d_out, int out_size, void* d_ws, size_t ws_size,
                              hipStream_t stream) {
  const float* x = (const float*)d_in[0];
  const float* x1 = (const float*)d_in[1];
  const float* x2 = (const float*)d_in[2];
  const float* bn1_g = (const float*)d_in[3];
  const float* bn1_b = (const float*)d_in[4];
  const float* bn1_m = (const float*)d_in[5];
  const float* bn1_v = (const float*)d_in[6];
  const float* bn2_g = (const float*)d_in[7];
  const float* bn2_b = (const float*)d_in[8];
  const float* bn2_m = (const float*)d_in[9];
  const float* bn2_v = (const float*)d_in[10];
  const float* kq1_w = (const float*)d_in[11];
  const float* kq1_b = (const float*)d_in[12];
  const float* kq2_w = (const float*)d_in[13];
  const float* kq2_b = (const float*)d_in[14];
  const float* v_w = (const float*)d_in[15];
  const float* v_b = (const float*)d_in[16];
  const float* out_w = (const float*)d_in[17];
  const float* out_b = (const float*)d_in[18];
  const float* bnl_g = (const float*)d_in[19];
  const float* bnl_b = (const float*)d_in[20];
  const float* bnl_m = (const float*)d_in[21];
  const float* bnl_v = (const float*)d_in[22];
  const float* w_scale = (const float*)d_in[23];

  char* ws = (char*)d_ws;
  const size_t QKV_SZ = (size_t)NB * 2 * NN * DD * 2;   // 4 MB each
  size_t off = 0;
  unsigned short* Qb = (unsigned short*)(ws + off); off += QKV_SZ;
  unsigned short* Kb = (unsigned short*)(ws + off); off += QKV_SZ;
  unsigned short* Vt = (unsigned short*)(ws + off); off += QKV_SZ;
  unsigned short* Ob = (unsigned short*)(ws + off); off += (size_t)NB * NN * 128 * 2;
  unsigned short* W1 = (unsigned short*)(ws + off); off += 128 * CC * 2;
  unsigned short* W2 = (unsigned short*)(ws + off); off += 128 * CC * 2;
  unsigned short* WV = (unsigned short*)(ws + off); off += 128 * CC * 2;
  unsigned short* WO = (unsigned short*)(ws + off); off += CC * 128 * 2;
  float* B1 = (float*)(ws + off); off += 512;
  float* B2 = (float*)(ws + off); off += 512;
  float* BV = (float*)(ws + off); off += 512;
  float* BO = (float*)(ws + off); off += 1024;
  if (ws_size < off) return;  // loud failure: output stays poisoned

  prep_kernel<<<16, 256, 0, stream>>>(
      kq1_w, kq1_b, kq2_w, kq2_b, v_w, v_b, out_w, out_b,
      bn1_g, bn1_b, bn1_m, bn1_v, bn2_g, bn2_b, bn2_m, bn2_v,
      bnl_g, bnl_b, bnl_m, bnl_v, w_scale,
      W1, W2, WV, WO, B1, B2, BV, BO);

  proj_kernel<<<dim3(64, 3, 4), 256, 0, stream>>>(
      x, x1, x2, W1, W2, WV, B1, B2, BV, Qb, Kb, Vt);

  attn_kernel<<<dim3(512, 1, 1), 256, 0, stream>>>(Qb, Kb, Vt, Ob);

  out_kernel<<<dim3(1024, 1, 1), 256, 0, stream>>>(Ob, WO, BO, x, (float*)d_out);
}

// Round 17
// 98.266 us; speedup vs baseline: 1.8319x; 1.0117x over previous
//
#include <hip/hip_runtime.h>

typedef short bf16x8 __attribute__((ext_vector_type(8)));
typedef float f32x4 __attribute__((ext_vector_type(4)));
typedef float f32x2 __attribute__((ext_vector_type(2)));
typedef unsigned short u16x4 __attribute__((ext_vector_type(4)));
typedef unsigned short u16x2 __attribute__((ext_vector_type(2)));

#define MFMA16(A, B, C) __builtin_amdgcn_mfma_f32_16x16x32_bf16((A), (B), (C), 0, 0, 0)

static constexpr int NB = 4;       // batch
static constexpr int CC = 256;     // channels (INC1 == INC2)
static constexpr int NN = 4096;    // H*W
static constexpr int DD = 64;      // head dim

__device__ __forceinline__ unsigned short f2bf(float f) {
  unsigned int u = __builtin_bit_cast(unsigned int, f);
  u += 0x7fffu + ((u >> 16) & 1u);
  return (unsigned short)(u >> 16);
}

__device__ __forceinline__ unsigned int pk2(float lo, float hi) {
  return (unsigned int)f2bf(lo) | ((unsigned int)f2bf(hi) << 16);
}

// T12 recipe: packed f32->bf16x2 convert (RNE), 1 instruction.
__device__ __forceinline__ unsigned int cvtpk(float lo, float hi) {
  unsigned int r;
  asm("v_cvt_pk_bf16_f32 %0, %1, %2" : "=v"(r) : "v"(lo), "v"(hi));
  return r;
}

// 3-input max: clang fuses nested fmaxf into v_max3_f32 (T17).
__device__ __forceinline__ float max3f(float a, float b, float c) {
  return fmaxf(fmaxf(a, b), c);
}

// LDS 16B-slot swizzle (R5-verified)
__device__ __forceinline__ int swz16(int row) {
  return ((row & 3) | ((((row >> 2) ^ (row >> 3)) & 1) << 2)) << 4;
}

// ---------------------------------------------------------------------------
// Kernel 1: fold BN into projection weights. Grid 16 (R11-verified).
// ---------------------------------------------------------------------------
__global__ __launch_bounds__(256) void prep_kernel(
    const float* __restrict__ kq1_w, const float* __restrict__ kq1_b,
    const float* __restrict__ kq2_w, const float* __restrict__ kq2_b,
    const float* __restrict__ v_w,   const float* __restrict__ v_b,
    const float* __restrict__ out_w, const float* __restrict__ out_b,
    const float* __restrict__ bn1_g, const float* __restrict__ bn1_b,
    const float* __restrict__ bn1_m, const float* __restrict__ bn1_v,
    const float* __restrict__ bn2_g, const float* __restrict__ bn2_b,
    const float* __restrict__ bn2_m, const float* __restrict__ bn2_v,
    const float* __restrict__ bnl_g, const float* __restrict__ bnl_b,
    const float* __restrict__ bnl_m, const float* __restrict__ bnl_v,
    const float* __restrict__ w_scale,
    unsigned short* __restrict__ W1, unsigned short* __restrict__ W2,
    unsigned short* __restrict__ WV, unsigned short* __restrict__ WO,
    float* __restrict__ B1, float* __restrict__ B2,
    float* __restrict__ BV, float* __restrict__ BO)
{
  int blk = blockIdx.x;
  int tid = threadIdx.x;
  int w = tid >> 6, lane = tid & 63;
  if (blk < 12) {
    int mat = blk >> 2, rg = blk & 3;
    const float* Wsrc = mat == 0 ? kq1_w : (mat == 1 ? kq2_w : v_w);
    const float* bsrc = mat == 0 ? kq1_b : (mat == 1 ? kq2_b : v_b);
    unsigned short* Wdst = mat == 0 ? W1 : (mat == 1 ? W2 : WV);
    float* Bdst = mat == 0 ? B1 : (mat == 1 ? B2 : BV);
    __shared__ float s_lds[256], o_lds[256];
    if (mat == 0) {
      float s = bn1_g[tid] * rsqrtf(bn1_v[tid] + 1e-5f);
      s_lds[tid] = s;
      o_lds[tid] = bn1_b[tid] - bn1_m[tid] * s;
    } else if (mat == 1) {
      float s = bn2_g[tid] * rsqrtf(bn2_v[tid] + 1e-5f);
      s_lds[tid] = s;
      o_lds[tid] = bn2_b[tid] - bn2_m[tid] * s;
    } else {
      s_lds[tid] = 1.f;
      o_lds[tid] = 0.f;
    }
    __syncthreads();
    int c = lane * 4;
    for (int row = rg * 32 + w; row < rg * 32 + 32; row += 4) {
      f32x4 wv = *(const f32x4*)(Wsrc + row * CC + c);
      u16x4 o;
      float bacc = 0.f;
#pragma unroll
      for (int j = 0; j < 4; ++j) {
        o[j] = f2bf(wv[j] * s_lds[c + j]);
        bacc += wv[j] * o_lds[c + j];
      }
      *(u16x4*)(Wdst + row * CC + c) = o;
#pragma unroll
      for (int off = 1; off < 64; off <<= 1) bacc += __shfl_xor(bacc, off);
      if (lane == 0) Bdst[row] = bsrc[row] + bacc;
    }
  } else {
    int rg = blk - 12;
    float ws = w_scale[0];
    if (rg == 0) {
      float s = bnl_g[tid] * rsqrtf(bnl_v[tid] + 1e-5f);
      BO[tid] = ws * (out_b[tid] * s + bnl_b[tid] - bnl_m[tid] * s);
    }
    int d = lane * 2;
    for (int row = rg * 64 + w; row < rg * 64 + 64; row += 4) {
      float s = ws * bnl_g[row] * rsqrtf(bnl_v[row] + 1e-5f);
      f32x2 wv = *(const f32x2*)(out_w + row * 128 + d);
      u16x2 o;
      o[0] = f2bf(s * wv[0]);
      o[1] = f2bf(s * wv[1]);
      *(u16x2*)(WO + row * 128 + d) = o;
    }
  }
}

// ---------------------------------------------------------------------------
// Kernel 2: FUSED transpose + projection (R14/R15-verified) + one-subtile-
// ahead global loads (T14): cb+1's loads issue before cb's barriers, so the
// HBM latency drains under the transpose/pack phase.
// ---------------------------------------------------------------------------
__global__ __launch_bounds__(256) void proj_kernel(
    const float* __restrict__ x, const float* __restrict__ x1,
    const float* __restrict__ x2,
    const unsigned short* __restrict__ W1, const unsigned short* __restrict__ W2,
    const unsigned short* __restrict__ WV,
    const float* __restrict__ B1, const float* __restrict__ B2, const float* __restrict__ BV,
    unsigned short* __restrict__ Qb, unsigned short* __restrict__ Kb,
    unsigned short* __restrict__ Vt)
{
  int nt = blockIdx.x;
  int mat = blockIdx.y;
  int b = blockIdx.z;
  const float* src = mat == 0 ? x1 : (mat == 1 ? x2 : x);
  const unsigned short* W = mat == 0 ? W1 : (mat == 1 ? W2 : WV);
  const float* Bi = mat == 0 ? B1 : (mat == 1 ? B2 : BV);
  int t = threadIdx.x;
  int w = t >> 6, lane = t & 63;
  int lhi = lane >> 4, llo = lane & 15;

  __shared__ float ftile[64][65];                 // f32 transpose staging
  __shared__ unsigned short xt[64 * 256];         // bf16 (n,c) tile, swizzled

  int cl = t >> 2, n0q = (t & 3) * 16;            // global-read mapping
  int nl = t >> 2, c0 = (t & 3) * 16;             // pack mapping

  f32x4 ld[2][4];
#define LOADSUB(CB, BUF)                                                      \
  {                                                                           \
    const float* s_ = src + ((size_t)b * CC + (CB) * 64 + cl) * NN + nt * 64 + n0q; \
    ld[BUF][0] = *(const f32x4*)(s_);                                         \
    ld[BUF][1] = *(const f32x4*)(s_ + 4);                                     \
    ld[BUF][2] = *(const f32x4*)(s_ + 8);                                     \
    ld[BUF][3] = *(const f32x4*)(s_ + 12);                                    \
  }

  LOADSUB(0, 0);
#pragma unroll
  for (int cb = 0; cb < 4; ++cb) {
    if (cb < 3) LOADSUB(cb + 1, (cb + 1) & 1);    // issue next early (T14)
    if (cb) __syncthreads();                      // prev pack done
    const f32x4* v = ld[cb & 1];
#pragma unroll
    for (int j = 0; j < 4; ++j) {
      ftile[cl][n0q + j] = v[0][j];
      ftile[cl][n0q + 4 + j] = v[1][j];
      ftile[cl][n0q + 8 + j] = v[2][j];
      ftile[cl][n0q + 12 + j] = v[3][j];
    }
    __syncthreads();
    alignas(16) unsigned short tmp[16];
#pragma unroll
    for (int j = 0; j < 16; ++j) tmp[j] = f2bf(ftile[c0 + j][nl]);
    int rowswz = (nl & 7) << 4;
    char* base = (char*)xt + nl * 512;
    *(bf16x8*)(base + ((cb * 128 + c0 * 2) ^ rowswz)) = *(const bf16x8*)(tmp);
    *(bf16x8*)(base + ((cb * 128 + c0 * 2 + 16) ^ rowswz)) = *(const bf16x8*)(tmp + 8);
  }
  __syncthreads();

  // ---- MFMA: C(128 x 64n) = Weff(128x256) @ xt(n,256)^T ----
  int ob = w * 32;
  f32x4 acc[2][4] = {};
#pragma unroll
  for (int kc = 0; kc < 8; ++kc) {
    bf16x8 af[2], bfr[4];
#pragma unroll
    for (int ot = 0; ot < 2; ++ot)
      af[ot] = *(const bf16x8*)(W + (size_t)(ob + ot * 16 + llo) * CC + kc * 32 + lhi * 8);
#pragma unroll
    for (int nn = 0; nn < 4; ++nn) {
      int n = nn * 16 + llo;
      bfr[nn] = *(const bf16x8*)((char*)xt + n * 512 + ((kc * 64 + lhi * 16) ^ ((n & 7) << 4)));
    }
#pragma unroll
    for (int ot = 0; ot < 2; ++ot)
#pragma unroll
      for (int nn = 0; nn < 4; ++nn)
        acc[ot][nn] = MFMA16(af[ot], bfr[nn], acc[ot][nn]);
  }

#pragma unroll
  for (int ot = 0; ot < 2; ++ot)
#pragma unroll
    for (int nn = 0; nn < 4; ++nn) {
      int o0 = ob + ot * 16 + lhi * 4;
      int n = nt * 64 + nn * 16 + llo;
      float v0 = acc[ot][nn][0] + Bi[o0 + 0];
      float v1 = acc[ot][nn][1] + Bi[o0 + 1];
      float v2 = acc[ot][nn][2] + Bi[o0 + 2];
      float v3 = acc[ot][nn][3] + Bi[o0 + 3];
      if (mat < 2) {
        int blk = o0 >> 5;               // const over r: 0:K a0 1:Q a0 2:K a1 3:Q a1
        int aa = blk >> 1;
        int d0 = (o0 & 31) + mat * 32;
        if (blk & 1) {
          v0 *= 0.18033688011f; v1 *= 0.18033688011f;   // 0.125 * log2(e)
          v2 *= 0.18033688011f; v3 *= 0.18033688011f;
        }
        unsigned short* dstp = (blk & 1) ? Qb : Kb;
        unsigned int* p = (unsigned int*)(dstp + ((size_t)(b * 2 + aa) * NN + n) * DD + d0);
        p[0] = pk2(v0, v1);
        p[1] = pk2(v2, v3);
      } else {
        int aa = o0 >> 6;
        int d0 = o0 & 63;
        Vt[((size_t)(b * 2 + aa) * DD + d0 + 0) * NN + n] = f2bf(v0);
        Vt[((size_t)(b * 2 + aa) * DD + d0 + 1) * NN + n] = f2bf(v1);
        Vt[((size_t)(b * 2 + aa) * DD + d0 + 2) * NN + n] = f2bf(v2);
        Vt[((size_t)(b * 2 + aa) * DD + d0 + 3) * NN + n] = f2bf(v3);
      }
    }
}

// ---------------------------------------------------------------------------
// Kernel 3: flash attention — R16-verified (XCD pin, max3, hoisted stage)
// + lazy group-max: the 2 serialized shfl_xor run ONLY when some lane's
// local max exceeds m (same exact-skip condition; identical semantics).
// ---------------------------------------------------------------------------
__global__ __launch_bounds__(256, 2) void attn_kernel(
    const unsigned short* __restrict__ Qb, const unsigned short* __restrict__ Kb,
    const unsigned short* __restrict__ Vt, unsigned short* __restrict__ Ob)
{
  int i = blockIdx.x;
  int ba = i & 7;                       // head -> XCD pin (R15-verified)
  int qt = i >> 3;                      // 64-q tile
  int a = ba & 1;
  int b = ba >> 1;
  int tid = threadIdx.x;
  int w = tid >> 6;
  int lane = tid & 63;
  int lhi = lane >> 4, llo = lane & 15;
  int wq = w & 1, wk = w >> 1;

  __shared__ char lds[65536];           // [wk][buf][ K 8KB | V 8KB ]

  const unsigned short* Qg = Qb + ((size_t)ba * NN + qt * 64 + wq * 32) * DD;
  bf16x8 qf[2][2];
#pragma unroll
  for (int qh = 0; qh < 2; ++qh)
#pragma unroll
    for (int h = 0; h < 2; ++h)
      qf[qh][h] = *(const bf16x8*)(Qg + (size_t)(qh * 16 + llo) * DD + h * 32 + lhi * 8);

  const unsigned short* Kg = Kb + ((size_t)ba * NN + wk * 2048) * DD;
  const unsigned short* Vg = Vt + (size_t)ba * DD * NN + wk * 2048;

  f32x4 oacc[2][4] = {};
  float m[2] = {-1e30f, -1e30f}, lsum[2] = {0.f, 0.f};

  int t7 = tid & 127;
  int sr8 = t7 >> 3, scol = t7 & 7;

  f32x4 kreg[4], vreg[4];
#define STAGE_LOAD(IT)                                                        \
  {                                                                           \
    int kb_ = (IT) * 64;                                                      \
    _Pragma("unroll") for (int i_ = 0; i_ < 4; ++i_) {                        \
      int row = i_ * 16 + sr8;                                                \
      kreg[i_] = *(const f32x4*)(Kg + (size_t)(kb_ + row) * DD + scol * 8);   \
      vreg[i_] = *(const f32x4*)(Vg + (size_t)row * NN + kb_ + scol * 8);     \
    }                                                                         \
  }
#define STAGE_WRITE(BUF)                                                      \
  {                                                                           \
    char* base_ = lds + wk * 32768 + (BUF) * 16384;                           \
    _Pragma("unroll") for (int i_ = 0; i_ < 4; ++i_) {                        \
      int row = i_ * 16 + sr8;                                                \
      int swz = (scol * 16) ^ swz16(row);                                     \
      *(f32x4*)(base_ + row * 128 + swz) = kreg[i_];                          \
      *(f32x4*)(base_ + 8192 + row * 128 + swz) = vreg[i_];                   \
    }                                                                         \
  }

  STAGE_LOAD(0);
  STAGE_WRITE(0);
  __syncthreads();

  int cur = 0;
  for (int it = 0; it < 32; ++it) {
    if (it < 31) STAGE_LOAD(it + 1);
    const char* Ks = lds + wk * 32768 + cur * 16384;
    const char* Vs = Ks + 8192;

    // S^T = K_perm @ Q (K fragment shared by both qh)
    f32x4 s[2][4] = {};
    __builtin_amdgcn_s_setprio(1);
#pragma unroll
    for (int t = 0; t < 4; ++t) {
      int krow = (t & 1) * 32 + ((llo >> 2) << 3) + ((t >> 1) << 2) + (llo & 3);
      int ksz = swz16(krow);
      const char* kp = Ks + krow * 128;
      bf16x8 k0 = *(const bf16x8*)(kp + ((lhi * 16) ^ ksz));
      bf16x8 k1 = *(const bf16x8*)(kp + ((64 + lhi * 16) ^ ksz));
      s[0][t] = MFMA16(k0, qf[0][0], s[0][t]);
      s[0][t] = MFMA16(k1, qf[0][1], s[0][t]);
      s[1][t] = MFMA16(k0, qf[1][0], s[1][t]);
      s[1][t] = MFMA16(k1, qf[1][1], s[1][t]);
    }
    __builtin_amdgcn_s_setprio(0);

    // online softmax per qh (exp2 domain; lane owns one q per qh)
    union { unsigned int u[4]; bf16x8 v; } F0[2], F1[2];
#pragma unroll
    for (int qh = 0; qh < 2; ++qh) {
      // max3-structured LOCAL reduce (8 ops, depth 3)
      float g0 = max3f(s[qh][0][0], s[qh][0][1], s[qh][0][2]);
      float g1 = max3f(s[qh][0][3], s[qh][1][0], s[qh][1][1]);
      float g2 = max3f(s[qh][1][2], s[qh][1][3], s[qh][2][0]);
      float g3 = max3f(s[qh][2][1], s[qh][2][2], s[qh][2][3]);
      float g4 = max3f(s[qh][3][0], s[qh][3][1], s[qh][3][2]);
      float h0 = max3f(g0, g1, g2);
      float h1 = max3f(g3, g4, s[qh][3][3]);
      float pmL = fmaxf(h0, h1);
      // lazy group-max: group max > m  <=>  some lane's local max > m
      if (__any(pmL > m[qh])) {
        float pm = fmaxf(pmL, __shfl_xor(pmL, 16));
        pm = fmaxf(pm, __shfl_xor(pm, 32));
        float mn = fmaxf(m[qh], pm);
        float al = __builtin_amdgcn_exp2f(m[qh] - mn);
        m[qh] = mn;
        lsum[qh] *= al;
#pragma unroll
        for (int dt = 0; dt < 4; ++dt)
#pragma unroll
          for (int r = 0; r < 4; ++r) oacc[qh][dt][r] *= al;
      }
#pragma unroll
      for (int t = 0; t < 4; ++t)
#pragma unroll
        for (int r = 0; r < 4; ++r)
          s[qh][t][r] = __builtin_amdgcn_exp2f(s[qh][t][r] - m[qh]);
      float p0 = (s[qh][0][0] + s[qh][0][1]) + (s[qh][0][2] + s[qh][0][3]);
      float p1 = (s[qh][1][0] + s[qh][1][1]) + (s[qh][1][2] + s[qh][1][3]);
      float p2 = (s[qh][2][0] + s[qh][2][1]) + (s[qh][2][2] + s[qh][2][3]);
      float p3 = (s[qh][3][0] + s[qh][3][1]) + (s[qh][3][2] + s[qh][3][3]);
      lsum[qh] += (p0 + p1) + (p2 + p3);

      F0[qh].u[0] = cvtpk(s[qh][0][0], s[qh][0][1]); F0[qh].u[1] = cvtpk(s[qh][0][2], s[qh][0][3]);
      F0[qh].u[2] = cvtpk(s[qh][2][0], s[qh][2][1]); F0[qh].u[3] = cvtpk(s[qh][2][2], s[qh][2][3]);
      F1[qh].u[0] = cvtpk(s[qh][1][0], s[qh][1][1]); F1[qh].u[1] = cvtpk(s[qh][1][2], s[qh][1][3]);
      F1[qh].u[2] = cvtpk(s[qh][3][0], s[qh][3][1]); F1[qh].u[3] = cvtpk(s[qh][3][2], s[qh][3][3]);
    }

    // hoisted: stage next tile into the other buffer BEFORE PV so the
    // ds_writes drain under the PV MFMA latency (no hazard: disjoint buffer)
    if (it < 31) STAGE_WRITE(cur ^ 1);

    // O^T += V^T @ P^T (V fragment shared by both qh)
    __builtin_amdgcn_s_setprio(1);
#pragma unroll
    for (int dt = 0; dt < 4; ++dt) {
      int vrow = dt * 16 + llo;
      int vsz = swz16(vrow);
      const char* vp = Vs + vrow * 128;
      bf16x8 v0 = *(const bf16x8*)(vp + ((lhi * 16) ^ vsz));
      bf16x8 v1 = *(const bf16x8*)(vp + ((64 + lhi * 16) ^ vsz));
      oacc[0][dt] = MFMA16(v0, F0[0].v, oacc[0][dt]);
      oacc[0][dt] = MFMA16(v1, F1[0].v, oacc[0][dt]);
      oacc[1][dt] = MFMA16(v0, F0[1].v, oacc[1][dt]);
      oacc[1][dt] = MFMA16(v1, F1[1].v, oacc[1][dt]);
    }
    __builtin_amdgcn_s_setprio(0);

    __syncthreads();                    // publish writes + fence next iter
    cur ^= 1;
  }

#pragma unroll
  for (int qh = 0; qh < 2; ++qh) {
    lsum[qh] += __shfl_xor(lsum[qh], 16);
    lsum[qh] += __shfl_xor(lsum[qh], 32);
  }

  // merge the two wk-halves via LDS (stride 65)
  float* mO = (float*)lds;               // [64 q][65]
  float* mM = (float*)lds + 64 * 65;     // [64]
  float* mL = mM + 64;
  if (wk == 1) {
#pragma unroll
    for (int qh = 0; qh < 2; ++qh) {
      int ql = wq * 32 + qh * 16 + llo;
#pragma unroll
      for (int dt = 0; dt < 4; ++dt)
#pragma unroll
        for (int r = 0; r < 4; ++r)
          mO[ql * 65 + dt * 16 + lhi * 4 + r] = oacc[qh][dt][r];
      if (lhi == 0) { mM[ql] = m[qh]; mL[ql] = lsum[qh]; }
    }
  }
  __syncthreads();
  if (wk == 0) {
#pragma unroll
    for (int qh = 0; qh < 2; ++qh) {
      int ql = wq * 32 + qh * 16 + llo;
      float m2 = mM[ql], l2 = mL[ql];
      float mf = fmaxf(m[qh], m2);
      float e1 = __builtin_amdgcn_exp2f(m[qh] - mf);
      float e2 = __builtin_amdgcn_exp2f(m2 - mf);
      float inv = 1.f / (lsum[qh] * e1 + l2 * e2);
      int qglob = qt * 64 + ql;
      unsigned int* dst = (unsigned int*)(Ob + ((size_t)b * NN + qglob) * 128 + a * 64);
      const float* mOr = mO + ql * 65;
#pragma unroll
      for (int dt = 0; dt < 4; ++dt) {
        int d0 = dt * 16 + lhi * 4;
        float v0 = (oacc[qh][dt][0] * e1 + mOr[d0 + 0] * e2) * inv;
        float v1 = (oacc[qh][dt][1] * e1 + mOr[d0 + 1] * e2) * inv;
        float v2 = (oacc[qh][dt][2] * e1 + mOr[d0 + 2] * e2) * inv;
        float v3 = (oacc[qh][dt][3] * e1 + mOr[d0 + 3] * e2) * inv;
        dst[dt * 8 + lhi * 2] = pk2(v0, v1);
        dst[dt * 8 + lhi * 2 + 1] = pk2(v2, v3);
      }
    }
  }
}

// ---------------------------------------------------------------------------
// Kernel 4: OUT[b,c,n] = sum_d WO[c,d]*O[b,n,d] + BO[c] + x[b,c,n]
// 1D XCD-congruent grid (R16-verified).
// ---------------------------------------------------------------------------
__global__ __launch_bounds__(256) void out_kernel(
    const unsigned short* __restrict__ Ob, const unsigned short* __restrict__ WO,
    const float* __restrict__ BO, const float* __restrict__ x,
    float* __restrict__ out)
{
  int id = blockIdx.x;
  int ct = id >> 8;
  int r8 = id & 255;
  int nt = r8 >> 2;
  int b = r8 & 3;
  int w = threadIdx.x >> 6, lane = threadIdx.x & 63;
  int lhi = lane >> 4, llo = lane & 15;
  int cb = ct * 64 + w * 16;

  f32x4 acc[4] = {};
#pragma unroll
  for (int kc = 0; kc < 4; ++kc) {
    bf16x8 af = *(const bf16x8*)(WO + (size_t)(cb + llo) * 128 + kc * 32 + lhi * 8);
#pragma unroll
    for (int nn = 0; nn < 4; ++nn) {
      bf16x8 bfr = *(const bf16x8*)(Ob + ((size_t)b * NN + nt * 64 + nn * 16 + llo) * 128 + kc * 32 + lhi * 8);
      acc[nn] = MFMA16(af, bfr, acc[nn]);
    }
  }
#pragma unroll
  for (int nn = 0; nn < 4; ++nn)
#pragma unroll
    for (int r = 0; r < 4; ++r) {
      int c = cb + lhi * 4 + r;
      int n = nt * 64 + nn * 16 + llo;
      size_t idx = ((size_t)b * CC + c) * NN + n;
      out[idx] = acc[nn][r] + BO[c] + x[idx];
    }
}

// ---------------------------------------------------------------------------
extern "C" void kernel_launch(void* const* d_in, const int* in_sizes, int n_in,
                              void* d_out, int out_size, void* d_ws, size_t ws_size,
                              hipStream_t stream) {
  const float* x = (const float*)d_in[0];
  const float* x1 = (const float*)d_in[1];
  const float* x2 = (const float*)d_in[2];
  const float* bn1_g = (const float*)d_in[3];
  const float* bn1_b = (const float*)d_in[4];
  const float* bn1_m = (const float*)d_in[5];
  const float* bn1_v = (const float*)d_in[6];
  const float* bn2_g = (const float*)d_in[7];
  const float* bn2_b = (const float*)d_in[8];
  const float* bn2_m = (const float*)d_in[9];
  const float* bn2_v = (const float*)d_in[10];
  const float* kq1_w = (const float*)d_in[11];
  const float* kq1_b = (const float*)d_in[12];
  const float* kq2_w = (const float*)d_in[13];
  const float* kq2_b = (const float*)d_in[14];
  const float* v_w = (const float*)d_in[15];
  const float* v_b = (const float*)d_in[16];
  const float* out_w = (const float*)d_in[17];
  const float* out_b = (const float*)d_in[18];
  const float* bnl_g = (const float*)d_in[19];
  const float* bnl_b = (const float*)d_in[20];
  const float* bnl_m = (const float*)d_in[21];
  const float* bnl_v = (const float*)d_in[22];
  const float* w_scale = (const float*)d_in[23];

  char* ws = (char*)d_ws;
  const size_t QKV_SZ = (size_t)NB * 2 * NN * DD * 2;   // 4 MB each
  size_t off = 0;
  unsigned short* Qb = (unsigned short*)(ws + off); off += QKV_SZ;
  unsigned short* Kb = (unsigned short*)(ws + off); off += QKV_SZ;
  unsigned short* Vt = (unsigned short*)(ws + off); off += QKV_SZ;
  unsigned short* Ob = (unsigned short*)(ws + off); off += (size_t)NB * NN * 128 * 2;
  unsigned short* W1 = (unsigned short*)(ws + off); off += 128 * CC * 2;
  unsigned short* W2 = (unsigned short*)(ws + off); off += 128 * CC * 2;
  unsigned short* WV = (unsigned short*)(ws + off); off += 128 * CC * 2;
  unsigned short* WO = (unsigned short*)(ws + off); off += CC * 128 * 2;
  float* B1 = (float*)(ws + off); off += 512;
  float* B2 = (float*)(ws + off); off += 512;
  float* BV = (float*)(ws + off); off += 512;
  float* BO = (float*)(ws + off); off += 1024;
  if (ws_size < off) return;  // loud failure: output stays poisoned

  prep_kernel<<<16, 256, 0, stream>>>(
      kq1_w, kq1_b, kq2_w, kq2_b, v_w, v_b, out_w, out_b,
      bn1_g, bn1_b, bn1_m, bn1_v, bn2_g, bn2_b, bn2_m, bn2_v,
      bnl_g, bnl_b, bnl_m, bnl_v, w_scale,
      W1, W2, WV, WO, B1, B2, BV, BO);

  proj_kernel<<<dim3(64, 3, 4), 256, 0, stream>>>(
      x, x1, x2, W1, W2, WV, B1, B2, BV, Qb, Kb, Vt);

  attn_kernel<<<dim3(512, 1, 1), 256, 0, stream>>>(Qb, Kb, Vt, Ob);

  out_kernel<<<dim3(1024, 1, 1), 256, 0, stream>>>(Ob, WO, BO, x, (float*)d_out);
}

// Round 19
// 98.063 us; speedup vs baseline: 1.8357x; 1.0021x over previous
//
#include <hip/hip_runtime.h>

typedef short bf16x8 __attribute__((ext_vector_type(8)));
typedef float f32x4 __attribute__((ext_vector_type(4)));
typedef float f32x2 __attribute__((ext_vector_type(2)));
typedef unsigned short u16x4 __attribute__((ext_vector_type(4)));
typedef unsigned short u16x2 __attribute__((ext_vector_type(2)));

#define MFMA16(A, B, C) __builtin_amdgcn_mfma_f32_16x16x32_bf16((A), (B), (C), 0, 0, 0)

static constexpr int NB = 4;       // batch
static constexpr int CC = 256;     // channels (INC1 == INC2)
static constexpr int NN = 4096;    // H*W
static constexpr int DD = 64;      // head dim

__device__ __forceinline__ unsigned short f2bf(float f) {
  unsigned int u = __builtin_bit_cast(unsigned int, f);
  u += 0x7fffu + ((u >> 16) & 1u);
  return (unsigned short)(u >> 16);
}

__device__ __forceinline__ unsigned int pk2(float lo, float hi) {
  return (unsigned int)f2bf(lo) | ((unsigned int)f2bf(hi) << 16);
}

// T12 recipe: packed f32->bf16x2 convert (RNE), 1 instruction.
__device__ __forceinline__ unsigned int cvtpk(float lo, float hi) {
  unsigned int r;
  asm("v_cvt_pk_bf16_f32 %0, %1, %2" : "=v"(r) : "v"(lo), "v"(hi));
  return r;
}

// 3-input max: clang fuses nested fmaxf into v_max3_f32 (T17).
__device__ __forceinline__ float max3f(float a, float b, float c) {
  return fmaxf(fmaxf(a, b), c);
}

// LDS 16B-slot swizzle (R5-verified)
__device__ __forceinline__ int swz16(int row) {
  return ((row & 3) | ((((row >> 2) ^ (row >> 3)) & 1) << 2)) << 4;
}

// ---------------------------------------------------------------------------
// Kernel 1: fold BN into projection weights. Grid 16 (R11-verified).
// ---------------------------------------------------------------------------
__global__ __launch_bounds__(256) void prep_kernel(
    const float* __restrict__ kq1_w, const float* __restrict__ kq1_b,
    const float* __restrict__ kq2_w, const float* __restrict__ kq2_b,
    const float* __restrict__ v_w,   const float* __restrict__ v_b,
    const float* __restrict__ out_w, const float* __restrict__ out_b,
    const float* __restrict__ bn1_g, const float* __restrict__ bn1_b,
    const float* __restrict__ bn1_m, const float* __restrict__ bn1_v,
    const float* __restrict__ bn2_g, const float* __restrict__ bn2_b,
    const float* __restrict__ bn2_m, const float* __restrict__ bn2_v,
    const float* __restrict__ bnl_g, const float* __restrict__ bnl_b,
    const float* __restrict__ bnl_m, const float* __restrict__ bnl_v,
    const float* __restrict__ w_scale,
    unsigned short* __restrict__ W1, unsigned short* __restrict__ W2,
    unsigned short* __restrict__ WV, unsigned short* __restrict__ WO,
    float* __restrict__ B1, float* __restrict__ B2,
    float* __restrict__ BV, float* __restrict__ BO)
{
  int blk = blockIdx.x;
  int tid = threadIdx.x;
  int w = tid >> 6, lane = tid & 63;
  if (blk < 12) {
    int mat = blk >> 2, rg = blk & 3;
    const float* Wsrc = mat == 0 ? kq1_w : (mat == 1 ? kq2_w : v_w);
    const float* bsrc = mat == 0 ? kq1_b : (mat == 1 ? kq2_b : v_b);
    unsigned short* Wdst = mat == 0 ? W1 : (mat == 1 ? W2 : WV);
    float* Bdst = mat == 0 ? B1 : (mat == 1 ? B2 : BV);
    __shared__ float s_lds[256], o_lds[256];
    if (mat == 0) {
      float s = bn1_g[tid] * rsqrtf(bn1_v[tid] + 1e-5f);
      s_lds[tid] = s;
      o_lds[tid] = bn1_b[tid] - bn1_m[tid] * s;
    } else if (mat == 1) {
      float s = bn2_g[tid] * rsqrtf(bn2_v[tid] + 1e-5f);
      s_lds[tid] = s;
      o_lds[tid] = bn2_b[tid] - bn2_m[tid] * s;
    } else {
      s_lds[tid] = 1.f;
      o_lds[tid] = 0.f;
    }
    __syncthreads();
    int c = lane * 4;
    for (int row = rg * 32 + w; row < rg * 32 + 32; row += 4) {
      f32x4 wv = *(const f32x4*)(Wsrc + row * CC + c);
      u16x4 o;
      float bacc = 0.f;
#pragma unroll
      for (int j = 0; j < 4; ++j) {
        o[j] = f2bf(wv[j] * s_lds[c + j]);
        bacc += wv[j] * o_lds[c + j];
      }
      *(u16x4*)(Wdst + row * CC + c) = o;
#pragma unroll
      for (int off = 1; off < 64; off <<= 1) bacc += __shfl_xor(bacc, off);
      if (lane == 0) Bdst[row] = bsrc[row] + bacc;
    }
  } else {
    int rg = blk - 12;
    float ws = w_scale[0];
    if (rg == 0) {
      float s = bnl_g[tid] * rsqrtf(bnl_v[tid] + 1e-5f);
      BO[tid] = ws * (out_b[tid] * s + bnl_b[tid] - bnl_m[tid] * s);
    }
    int d = lane * 2;
    for (int row = rg * 64 + w; row < rg * 64 + 64; row += 4) {
      float s = ws * bnl_g[row] * rsqrtf(bnl_v[row] + 1e-5f);
      f32x2 wv = *(const f32x2*)(out_w + row * 128 + d);
      u16x2 o;
      o[0] = f2bf(s * wv[0]);
      o[1] = f2bf(s * wv[1]);
      *(u16x2*)(WO + row * 128 + d) = o;
    }
  }
}

// ---------------------------------------------------------------------------
// Kernel 2: FUSED transpose + projection (R17-verified).
// ---------------------------------------------------------------------------
__global__ __launch_bounds__(256) void proj_kernel(
    const float* __restrict__ x, const float* __restrict__ x1,
    const float* __restrict__ x2,
    const unsigned short* __restrict__ W1, const unsigned short* __restrict__ W2,
    const unsigned short* __restrict__ WV,
    const float* __restrict__ B1, const float* __restrict__ B2, const float* __restrict__ BV,
    unsigned short* __restrict__ Qb, unsigned short* __restrict__ Kb,
    unsigned short* __restrict__ Vt)
{
  int nt = blockIdx.x;
  int mat = blockIdx.y;
  int b = blockIdx.z;
  const float* src = mat == 0 ? x1 : (mat == 1 ? x2 : x);
  const unsigned short* W = mat == 0 ? W1 : (mat == 1 ? W2 : WV);
  const float* Bi = mat == 0 ? B1 : (mat == 1 ? B2 : BV);
  int t = threadIdx.x;
  int w = t >> 6, lane = t & 63;
  int lhi = lane >> 4, llo = lane & 15;

  __shared__ float ftile[64][65];                 // f32 transpose staging
  __shared__ unsigned short xt[64 * 256];         // bf16 (n,c) tile, swizzled

  int cl = t >> 2, n0q = (t & 3) * 16;            // global-read mapping
  int nl = t >> 2, c0 = (t & 3) * 16;             // pack mapping

  f32x4 ld[2][4];
#define LOADSUB(CB, BUF)                                                      \
  {                                                                           \
    const float* s_ = src + ((size_t)b * CC + (CB) * 64 + cl) * NN + nt * 64 + n0q; \
    ld[BUF][0] = *(const f32x4*)(s_);                                         \
    ld[BUF][1] = *(const f32x4*)(s_ + 4);                                     \
    ld[BUF][2] = *(const f32x4*)(s_ + 8);                                     \
    ld[BUF][3] = *(const f32x4*)(s_ + 12);                                    \
  }

  LOADSUB(0, 0);
#pragma unroll
  for (int cb = 0; cb < 4; ++cb) {
    if (cb < 3) LOADSUB(cb + 1, (cb + 1) & 1);    // issue next early (T14)
    if (cb) __syncthreads();                      // prev pack done
    const f32x4* v = ld[cb & 1];
#pragma unroll
    for (int j = 0; j < 4; ++j) {
      ftile[cl][n0q + j] = v[0][j];
      ftile[cl][n0q + 4 + j] = v[1][j];
      ftile[cl][n0q + 8 + j] = v[2][j];
      ftile[cl][n0q + 12 + j] = v[3][j];
    }
    __syncthreads();
    alignas(16) unsigned short tmp[16];
#pragma unroll
    for (int j = 0; j < 16; ++j) tmp[j] = f2bf(ftile[c0 + j][nl]);
    int rowswz = (nl & 7) << 4;
    char* base = (char*)xt + nl * 512;
    *(bf16x8*)(base + ((cb * 128 + c0 * 2) ^ rowswz)) = *(const bf16x8*)(tmp);
    *(bf16x8*)(base + ((cb * 128 + c0 * 2 + 16) ^ rowswz)) = *(const bf16x8*)(tmp + 8);
  }
  __syncthreads();

  // ---- MFMA: C(128 x 64n) = Weff(128x256) @ xt(n,256)^T ----
  int ob = w * 32;
  f32x4 acc[2][4] = {};
#pragma unroll
  for (int kc = 0; kc < 8; ++kc) {
    bf16x8 af[2], bfr[4];
#pragma unroll
    for (int ot = 0; ot < 2; ++ot)
      af[ot] = *(const bf16x8*)(W + (size_t)(ob + ot * 16 + llo) * CC + kc * 32 + lhi * 8);
#pragma unroll
    for (int nn = 0; nn < 4; ++nn) {
      int n = nn * 16 + llo;
      bfr[nn] = *(const bf16x8*)((char*)xt + n * 512 + ((kc * 64 + lhi * 16) ^ ((n & 7) << 4)));
    }
#pragma unroll
    for (int ot = 0; ot < 2; ++ot)
#pragma unroll
      for (int nn = 0; nn < 4; ++nn)
        acc[ot][nn] = MFMA16(af[ot], bfr[nn], acc[ot][nn]);
  }

#pragma unroll
  for (int ot = 0; ot < 2; ++ot)
#pragma unroll
    for (int nn = 0; nn < 4; ++nn) {
      int o0 = ob + ot * 16 + lhi * 4;
      int n = nt * 64 + nn * 16 + llo;
      float v0 = acc[ot][nn][0] + Bi[o0 + 0];
      float v1 = acc[ot][nn][1] + Bi[o0 + 1];
      float v2 = acc[ot][nn][2] + Bi[o0 + 2];
      float v3 = acc[ot][nn][3] + Bi[o0 + 3];
      if (mat < 2) {
        int blk = o0 >> 5;               // const over r: 0:K a0 1:Q a0 2:K a1 3:Q a1
        int aa = blk >> 1;
        int d0 = (o0 & 31) + mat * 32;
        if (blk & 1) {
          v0 *= 0.18033688011f; v1 *= 0.18033688011f;   // 0.125 * log2(e)
          v2 *= 0.18033688011f; v3 *= 0.18033688011f;
        }
        unsigned short* dstp = (blk & 1) ? Qb : Kb;
        unsigned int* p = (unsigned int*)(dstp + ((size_t)(b * 2 + aa) * NN + n) * DD + d0);
        p[0] = pk2(v0, v1);
        p[1] = pk2(v2, v3);
      } else {
        int aa = o0 >> 6;
        int d0 = o0 & 63;
        Vt[((size_t)(b * 2 + aa) * DD + d0 + 0) * NN + n] = f2bf(v0);
        Vt[((size_t)(b * 2 + aa) * DD + d0 + 1) * NN + n] = f2bf(v1);
        Vt[((size_t)(b * 2 + aa) * DD + d0 + 2) * NN + n] = f2bf(v2);
        Vt[((size_t)(b * 2 + aa) * DD + d0 + 3) * NN + n] = f2bf(v3);
      }
    }
}

// ---------------------------------------------------------------------------
// Kernel 3: flash attention — R17-verified best (XCD head pin, max3 trees,
// hoisted STAGE_WRITE, lazy group-max, exp2 softmax, cvt_pk, defer-rescale,
// K/V double-buffer with 1 barrier/iter).
// ---------------------------------------------------------------------------
__global__ __launch_bounds__(256, 2) void attn_kernel(
    const unsigned short* __restrict__ Qb, const unsigned short* __restrict__ Kb,
    const unsigned short* __restrict__ Vt, unsigned short* __restrict__ Ob)
{
  int i = blockIdx.x;
  int ba = i & 7;                       // head -> XCD pin (R15-verified)
  int qt = i >> 3;                      // 64-q tile
  int a = ba & 1;
  int b = ba >> 1;
  int tid = threadIdx.x;
  int w = tid >> 6;
  int lane = tid & 63;
  int lhi = lane >> 4, llo = lane & 15;
  int wq = w & 1, wk = w >> 1;

  __shared__ char lds[65536];           // [wk][buf][ K 8KB | V 8KB ]

  const unsigned short* Qg = Qb + ((size_t)ba * NN + qt * 64 + wq * 32) * DD;
  bf16x8 qf[2][2];
#pragma unroll
  for (int qh = 0; qh < 2; ++qh)
#pragma unroll
    for (int h = 0; h < 2; ++h)
      qf[qh][h] = *(const bf16x8*)(Qg + (size_t)(qh * 16 + llo) * DD + h * 32 + lhi * 8);

  const unsigned short* Kg = Kb + ((size_t)ba * NN + wk * 2048) * DD;
  const unsigned short* Vg = Vt + (size_t)ba * DD * NN + wk * 2048;

  f32x4 oacc[2][4] = {};
  float m[2] = {-1e30f, -1e30f}, lsum[2] = {0.f, 0.f};

  int t7 = tid & 127;
  int sr8 = t7 >> 3, scol = t7 & 7;

  f32x4 kreg[4], vreg[4];
#define STAGE_LOAD(IT)                                                        \
  {                                                                           \
    int kb_ = (IT) * 64;                                                      \
    _Pragma("unroll") for (int i_ = 0; i_ < 4; ++i_) {                        \
      int row = i_ * 16 + sr8;                                                \
      kreg[i_] = *(const f32x4*)(Kg + (size_t)(kb_ + row) * DD + scol * 8);   \
      vreg[i_] = *(const f32x4*)(Vg + (size_t)row * NN + kb_ + scol * 8);     \
    }                                                                         \
  }
#define STAGE_WRITE(BUF)                                                      \
  {                                                                           \
    char* base_ = lds + wk * 32768 + (BUF) * 16384;                           \
    _Pragma("unroll") for (int i_ = 0; i_ < 4; ++i_) {                        \
      int row = i_ * 16 + sr8;                                                \
      int swz = (scol * 16) ^ swz16(row);                                     \
      *(f32x4*)(base_ + row * 128 + swz) = kreg[i_];                          \
      *(f32x4*)(base_ + 8192 + row * 128 + swz) = vreg[i_];                   \
    }                                                                         \
  }

  STAGE_LOAD(0);
  STAGE_WRITE(0);
  __syncthreads();

  int cur = 0;
  for (int it = 0; it < 32; ++it) {
    if (it < 31) STAGE_LOAD(it + 1);
    const char* Ks = lds + wk * 32768 + cur * 16384;
    const char* Vs = Ks + 8192;

    // S^T = K_perm @ Q (K fragment shared by both qh)
    f32x4 s[2][4] = {};
    __builtin_amdgcn_s_setprio(1);
#pragma unroll
    for (int t = 0; t < 4; ++t) {
      int krow = (t & 1) * 32 + ((llo >> 2) << 3) + ((t >> 1) << 2) + (llo & 3);
      int ksz = swz16(krow);
      const char* kp = Ks + krow * 128;
      bf16x8 k0 = *(const bf16x8*)(kp + ((lhi * 16) ^ ksz));
      bf16x8 k1 = *(const bf16x8*)(kp + ((64 + lhi * 16) ^ ksz));
      s[0][t] = MFMA16(k0, qf[0][0], s[0][t]);
      s[0][t] = MFMA16(k1, qf[0][1], s[0][t]);
      s[1][t] = MFMA16(k0, qf[1][0], s[1][t]);
      s[1][t] = MFMA16(k1, qf[1][1], s[1][t]);
    }
    __builtin_amdgcn_s_setprio(0);

    // online softmax per qh (exp2 domain; lane owns one q per qh)
    union { unsigned int u[4]; bf16x8 v; } F0[2], F1[2];
#pragma unroll
    for (int qh = 0; qh < 2; ++qh) {
      // max3-structured LOCAL reduce (8 ops, depth 3)
      float g0 = max3f(s[qh][0][0], s[qh][0][1], s[qh][0][2]);
      float g1 = max3f(s[qh][0][3], s[qh][1][0], s[qh][1][1]);
      float g2 = max3f(s[qh][1][2], s[qh][1][3], s[qh][2][0]);
      float g3 = max3f(s[qh][2][1], s[qh][2][2], s[qh][2][3]);
      float g4 = max3f(s[qh][3][0], s[qh][3][1], s[qh][3][2]);
      float h0 = max3f(g0, g1, g2);
      float h1 = max3f(g3, g4, s[qh][3][3]);
      float pmL = fmaxf(h0, h1);
      // lazy group-max: group max > m  <=>  some lane's local max > m
      if (__any(pmL > m[qh])) {
        float pm = fmaxf(pmL, __shfl_xor(pmL, 16));
        pm = fmaxf(pm, __shfl_xor(pm, 32));
        float mn = fmaxf(m[qh], pm);
        float al = __builtin_amdgcn_exp2f(m[qh] - mn);
        m[qh] = mn;
        lsum[qh] *= al;
#pragma unroll
        for (int dt = 0; dt < 4; ++dt)
#pragma unroll
          for (int r = 0; r < 4; ++r) oacc[qh][dt][r] *= al;
      }
#pragma unroll
      for (int t = 0; t < 4; ++t)
#pragma unroll
        for (int r = 0; r < 4; ++r)
          s[qh][t][r] = __builtin_amdgcn_exp2f(s[qh][t][r] - m[qh]);
      float p0 = (s[qh][0][0] + s[qh][0][1]) + (s[qh][0][2] + s[qh][0][3]);
      float p1 = (s[qh][1][0] + s[qh][1][1]) + (s[qh][1][2] + s[qh][1][3]);
      float p2 = (s[qh][2][0] + s[qh][2][1]) + (s[qh][2][2] + s[qh][2][3]);
      float p3 = (s[qh][3][0] + s[qh][3][1]) + (s[qh][3][2] + s[qh][3][3]);
      lsum[qh] += (p0 + p1) + (p2 + p3);

      F0[qh].u[0] = cvtpk(s[qh][0][0], s[qh][0][1]); F0[qh].u[1] = cvtpk(s[qh][0][2], s[qh][0][3]);
      F0[qh].u[2] = cvtpk(s[qh][2][0], s[qh][2][1]); F0[qh].u[3] = cvtpk(s[qh][2][2], s[qh][2][3]);
      F1[qh].u[0] = cvtpk(s[qh][1][0], s[qh][1][1]); F1[qh].u[1] = cvtpk(s[qh][1][2], s[qh][1][3]);
      F1[qh].u[2] = cvtpk(s[qh][3][0], s[qh][3][1]); F1[qh].u[3] = cvtpk(s[qh][3][2], s[qh][3][3]);
    }

    // hoisted: stage next tile into the other buffer BEFORE PV so the
    // ds_writes drain under the PV MFMA latency (no hazard: disjoint buffer)
    if (it < 31) STAGE_WRITE(cur ^ 1);

    // O^T += V^T @ P^T (V fragment shared by both qh)
    __builtin_amdgcn_s_setprio(1);
#pragma unroll
    for (int dt = 0; dt < 4; ++dt) {
      int vrow = dt * 16 + llo;
      int vsz = swz16(vrow);
      const char* vp = Vs + vrow * 128;
      bf16x8 v0 = *(const bf16x8*)(vp + ((lhi * 16) ^ vsz));
      bf16x8 v1 = *(const bf16x8*)(vp + ((64 + lhi * 16) ^ vsz));
      oacc[0][dt] = MFMA16(v0, F0[0].v, oacc[0][dt]);
      oacc[0][dt] = MFMA16(v1, F1[0].v, oacc[0][dt]);
      oacc[1][dt] = MFMA16(v0, F0[1].v, oacc[1][dt]);
      oacc[1][dt] = MFMA16(v1, F1[1].v, oacc[1][dt]);
    }
    __builtin_amdgcn_s_setprio(0);

    __syncthreads();                    // publish writes + fence next iter
    cur ^= 1;
  }

#pragma unroll
  for (int qh = 0; qh < 2; ++qh) {
    lsum[qh] += __shfl_xor(lsum[qh], 16);
    lsum[qh] += __shfl_xor(lsum[qh], 32);
  }

  // merge the two wk-halves via LDS (stride 65)
  float* mO = (float*)lds;               // [64 q][65]
  float* mM = (float*)lds + 64 * 65;     // [64]
  float* mL = mM + 64;
  if (wk == 1) {
#pragma unroll
    for (int qh = 0; qh < 2; ++qh) {
      int ql = wq * 32 + qh * 16 + llo;
#pragma unroll
      for (int dt = 0; dt < 4; ++dt)
#pragma unroll
        for (int r = 0; r < 4; ++r)
          mO[ql * 65 + dt * 16 + lhi * 4 + r] = oacc[qh][dt][r];
      if (lhi == 0) { mM[ql] = m[qh]; mL[ql] = lsum[qh]; }
    }
  }
  __syncthreads();
  if (wk == 0) {
#pragma unroll
    for (int qh = 0; qh < 2; ++qh) {
      int ql = wq * 32 + qh * 16 + llo;
      float m2 = mM[ql], l2 = mL[ql];
      float mf = fmaxf(m[qh], m2);
      float e1 = __builtin_amdgcn_exp2f(m[qh] - mf);
      float e2 = __builtin_amdgcn_exp2f(m2 - mf);
      float inv = 1.f / (lsum[qh] * e1 + l2 * e2);
      int qglob = qt * 64 + ql;
      unsigned int* dst = (unsigned int*)(Ob + ((size_t)b * NN + qglob) * 128 + a * 64);
      const float* mOr = mO + ql * 65;
#pragma unroll
      for (int dt = 0; dt < 4; ++dt) {
        int d0 = dt * 16 + lhi * 4;
        float v0 = (oacc[qh][dt][0] * e1 + mOr[d0 + 0] * e2) * inv;
        float v1 = (oacc[qh][dt][1] * e1 + mOr[d0 + 1] * e2) * inv;
        float v2 = (oacc[qh][dt][2] * e1 + mOr[d0 + 2] * e2) * inv;
        float v3 = (oacc[qh][dt][3] * e1 + mOr[d0 + 3] * e2) * inv;
        dst[dt * 8 + lhi * 2] = pk2(v0, v1);
        dst[dt * 8 + lhi * 2 + 1] = pk2(v2, v3);
      }
    }
  }
}

// ---------------------------------------------------------------------------
// Kernel 4: OUT[b,c,n] = sum_d WO[c,d]*O[b,n,d] + BO[c] + x[b,c,n]
// 1D XCD-congruent grid (R16-verified).
// ---------------------------------------------------------------------------
__global__ __launch_bounds__(256) void out_kernel(
    const unsigned short* __restrict__ Ob, const unsigned short* __restrict__ WO,
    const float* __restrict__ BO, const float* __restrict__ x,
    float* __restrict__ out)
{
  int id = blockIdx.x;
  int ct = id >> 8;
  int r8 = id & 255;
  int nt = r8 >> 2;
  int b = r8 & 3;
  int w = threadIdx.x >> 6, lane = threadIdx.x & 63;
  int lhi = lane >> 4, llo = lane & 15;
  int cb = ct * 64 + w * 16;

  f32x4 acc[4] = {};
#pragma unroll
  for (int kc = 0; kc < 4; ++kc) {
    bf16x8 af = *(const bf16x8*)(WO + (size_t)(cb + llo) * 128 + kc * 32 + lhi * 8);
#pragma unroll
    for (int nn = 0; nn < 4; ++nn) {
      bf16x8 bfr = *(const bf16x8*)(Ob + ((size_t)b * NN + nt * 64 + nn * 16 + llo) * 128 + kc * 32 + lhi * 8);
      acc[nn] = MFMA16(af, bfr, acc[nn]);
    }
  }
#pragma unroll
  for (int nn = 0; nn < 4; ++nn)
#pragma unroll
    for (int r = 0; r < 4; ++r) {
      int c = cb + lhi * 4 + r;
      int n = nt * 64 + nn * 16 + llo;
      size_t idx = ((size_t)b * CC + c) * NN + n;
      out[idx] = acc[nn][r] + BO[c] + x[idx];
    }
}

// ---------------------------------------------------------------------------
extern "C" void kernel_launch(void* const* d_in, const int* in_sizes, int n_in,
                              void* d_out, int out_size, void* d_ws, size_t ws_size,
                              hipStream_t stream) {
  const float* x = (const float*)d_in[0];
  const float* x1 = (const float*)d_in[1];
  const float* x2 = (const float*)d_in[2];
  const float* bn1_g = (const float*)d_in[3];
  const float* bn1_b = (const float*)d_in[4];
  const float* bn1_m = (const float*)d_in[5];
  const float* bn1_v = (const float*)d_in[6];
  const float* bn2_g = (const float*)d_in[7];
  const float* bn2_b = (const float*)d_in[8];
  const float* bn2_m = (const float*)d_in[9];
  const float* bn2_v = (const float*)d_in[10];
  const float* kq1_w = (const float*)d_in[11];
  const float* kq1_b = (const float*)d_in[12];
  const float* kq2_w = (const float*)d_in[13];
  const float* kq2_b = (const float*)d_in[14];
  const float* v_w = (const float*)d_in[15];
  const float* v_b = (const float*)d_in[16];
  const float* out_w = (const float*)d_in[17];
  const float* out_b = (const float*)d_in[18];
  const float* bnl_g = (const float*)d_in[19];
  const float* bnl_b = (const float*)d_in[20];
  const float* bnl_m = (const float*)d_in[21];
  const float* bnl_v = (const float*)d_in[22];
  const float* w_scale = (const float*)d_in[23];

  char* ws = (char*)d_ws;
  const size_t QKV_SZ = (size_t)NB * 2 * NN * DD * 2;   // 4 MB each
  size_t off = 0;
  unsigned short* Qb = (unsigned short*)(ws + off); off += QKV_SZ;
  unsigned short* Kb = (unsigned short*)(ws + off); off += QKV_SZ;
  unsigned short* Vt = (unsigned short*)(ws + off); off += QKV_SZ;
  unsigned short* Ob = (unsigned short*)(ws + off); off += (size_t)NB * NN * 128 * 2;
  unsigned short* W1 = (unsigned short*)(ws + off); off += 128 * CC * 2;
  unsigned short* W2 = (unsigned short*)(ws + off); off += 128 * CC * 2;
  unsigned short* WV = (unsigned short*)(ws + off); off += 128 * CC * 2;
  unsigned short* WO = (unsigned short*)(ws + off); off += CC * 128 * 2;
  float* B1 = (float*)(ws + off); off += 512;
  float* B2 = (float*)(ws + off); off += 512;
  float* BV = (float*)(ws + off); off += 512;
  float* BO = (float*)(ws + off); off += 1024;
  if (ws_size < off) return;  // loud failure: output stays poisoned

  prep_kernel<<<16, 256, 0, stream>>>(
      kq1_w, kq1_b, kq2_w, kq2_b, v_w, v_b, out_w, out_b,
      bn1_g, bn1_b, bn1_m, bn1_v, bn2_g, bn2_b, bn2_m, bn2_v,
      bnl_g, bnl_b, bnl_m, bnl_v, w_scale,
      W1, W2, WV, WO, B1, B2, BV, BO);

  proj_kernel<<<dim3(64, 3, 4), 256, 0, stream>>>(
      x, x1, x2, W1, W2, WV, B1, B2, BV, Qb, Kb, Vt);

  attn_kernel<<<dim3(512, 1, 1), 256, 0, stream>>>(Qb, Kb, Vt, Ob);

  out_kernel<<<dim3(1024, 1, 1), 256, 0, stream>>>(Ob, WO, BO, x, (float*)d_out);
}